// Round 3
// baseline (13421.173 us; speedup 1.0000x reference)
//
#include <hip/hip_runtime.h>
#include <hip/hip_bf16.h>
#include <math.h>

#define BATCH   4
#define CDIM    192
#define NHEADS  4
#define HDDIM   48
#define HH      128
#define WW      128
#define NPIX    16384      // 128*128
#define OQKV    768
#define HIDDEN_ 510
#define OFFN    1020
#define LNEPS   1e-5f

#define TS      16         // spatial tile 16x16
#define HS      18         // halo tile 18x18
#define HP      324        // HS*HS
#define CK      32         // Cin chunk
#define NCHUNK  6          // 192/32

typedef __hip_bfloat16 bf16;

__device__ __forceinline__ float b2f(bf16 v) { return __bfloat162float(v); }
__device__ __forceinline__ bf16  f2b(float v) { return __float2bfloat16(v); }
__device__ __forceinline__ float us2f(unsigned short u) {
  union { unsigned int i; float f; } cv; cv.i = ((unsigned int)u) << 16; return cv.f;
}

// ---------------- LayerNorm over channel dim (per pixel): f32 in -> bf16 out ----------------
__global__ __launch_bounds__(256) void ln_kernel(
    const float* __restrict__ x, const float* __restrict__ w,
    const float* __restrict__ b, bf16* __restrict__ y) {
  int idx = blockIdx.x * blockDim.x + threadIdx.x;   // over BATCH*NPIX
  if (idx >= BATCH * NPIX) return;
  int bb = idx / NPIX, n = idx % NPIX;
  const float* xp = x + ((size_t)bb * CDIM) * NPIX + n;
  float s = 0.f, ss = 0.f;
  for (int c = 0; c < CDIM; ++c) {
    float v = xp[(size_t)c * NPIX];
    s += v; ss += v * v;
  }
  float mu  = s * (1.f / CDIM);
  float var = ss * (1.f / CDIM) - mu * mu;
  float r   = rsqrtf(var + LNEPS);
  bf16* yp = y + ((size_t)bb * CDIM) * NPIX + n;
  for (int c = 0; c < CDIM; ++c) {
    yp[(size_t)c * NPIX] = f2b((xp[(size_t)c * NPIX] - mu) * r * w[c] + b[c]);
  }
}

// ---------------- fused conv1x1 (192->NACC ch) + dwconv3x3 [+ gelu-gate] ----------------
// grid: (64 tiles, Cblk, BATCH); block 256.
// GATED=false: writes OT channels (o0..o0+OT-1) of a Cout-channel tensor.
// GATED=true : conv computes OT chans at o0.. and OT chans at o0+510..; writes
//              gelu(dw(half1)) * dw(half2) into OT channels of a 510-ch tensor.
template <int OT, bool GATED>
__global__ __launch_bounds__(256) void fused_conv_dw_kernel(
    const bf16* __restrict__ in, const float* __restrict__ w,
    const float* __restrict__ dww, bf16* __restrict__ out, int Cout) {
  constexpr int NACC = GATED ? 2 * OT : OT;
  __shared__ unsigned short s_in[CK * HP];    // input halo chunk (bf16 bits)
  __shared__ float s_w[NACC * CK];            // conv weights chunk
  __shared__ float s_dw[NACC * 9];            // dw weights
  __shared__ float s_co[NACC * HP];           // conv output on halo

  const int tid = threadIdx.x;
  const int bb = blockIdx.z;
  const int o0 = blockIdx.y * OT;
  const int tile = blockIdx.x;
  const int ty0 = (tile >> 3) * TS;
  const int tx0 = (tile & 7) * TS;

  // dw weights (once)
  for (int i = tid; i < NACC * 9; i += 256) {
    int oi = i / 9, k = i % 9;
    int ch = GATED ? (oi < OT ? o0 + oi : o0 + (oi - OT) + HIDDEN_) : (o0 + oi);
    s_dw[i] = dww[(size_t)ch * 9 + k];
  }

  float acc0[NACC], acc1[NACC];
#pragma unroll
  for (int i = 0; i < NACC; ++i) { acc0[i] = 0.f; acc1[i] = 0.f; }

  const int hp2 = (tid < HP - 256) ? tid + 256 : tid;
  const unsigned short* inu = (const unsigned short*)in;

  for (int ch = 0; ch < NCHUNK; ++ch) {
    __syncthreads();
    // stage input halo chunk
    for (int idx = tid; idx < CK * HP; idx += 256) {
      int cc = idx / HP, hp = idx - cc * HP;
      int hy = hp / HS, hx = hp - hy * HS;
      int gy = ty0 + hy - 1, gx = tx0 + hx - 1;
      unsigned short v = 0;
      if (gy >= 0 && gy < HH && gx >= 0 && gx < WW)
        v = inu[((size_t)(bb * CDIM + ch * CK + cc)) * NPIX + gy * WW + gx];
      s_in[idx] = v;
    }
    // stage conv weights chunk
    for (int idx = tid; idx < NACC * CK; idx += 256) {
      int oi = idx / CK, cc = idx - oi * CK;
      int och = GATED ? (oi < OT ? o0 + oi : o0 + (oi - OT) + HIDDEN_) : (o0 + oi);
      s_w[idx] = w[(size_t)och * CDIM + ch * CK + cc];
    }
    __syncthreads();
#pragma unroll
    for (int cc = 0; cc < CK; ++cc) {
      float x0 = us2f(s_in[cc * HP + tid]);
      float x1 = us2f(s_in[cc * HP + hp2]);
#pragma unroll
      for (int oi = 0; oi < NACC; ++oi) {
        float wv = s_w[oi * CK + cc];
        acc0[oi] += wv * x0;
        acc1[oi] += wv * x1;
      }
    }
  }

  // conv-out to LDS
#pragma unroll
  for (int oi = 0; oi < NACC; ++oi) {
    s_co[oi * HP + tid] = acc0[oi];
    if (tid < HP - 256) s_co[oi * HP + tid + 256] = acc1[oi];
  }
  __syncthreads();

  // dwconv per tile pixel
  const int py = tid >> 4, px = tid & 15;
  const int gpix = (ty0 + py) * WW + (tx0 + px);

  if (!GATED) {
#pragma unroll
    for (int oi = 0; oi < OT; ++oi) {
      float a = 0.f;
#pragma unroll
      for (int ky = 0; ky < 3; ++ky)
#pragma unroll
        for (int kx = 0; kx < 3; ++kx)
          a += s_dw[oi * 9 + ky * 3 + kx] * s_co[oi * HP + (py + ky) * HS + px + kx];
      out[((size_t)(bb * Cout + o0 + oi)) * NPIX + gpix] = f2b(a);
    }
  } else {
#pragma unroll
    for (int oi = 0; oi < OT; ++oi) {
      float a1 = 0.f, a2 = 0.f;
#pragma unroll
      for (int ky = 0; ky < 3; ++ky)
#pragma unroll
        for (int kx = 0; kx < 3; ++kx) {
          int hidx = (py + ky) * HS + px + kx;
          a1 += s_dw[oi * 9 + ky * 3 + kx] * s_co[oi * HP + hidx];
          a2 += s_dw[(OT + oi) * 9 + ky * 3 + kx] * s_co[(OT + oi) * HP + hidx];
        }
      float ge = 0.5f * a1 * (1.f + erff(a1 * 0.70710678118f));
      out[((size_t)(bb * HIDDEN_ + o0 + oi)) * NPIX + gpix] = f2b(ge * a2);
    }
  }
}

// ---------------- 1x1 conv (bf16 in, f32 weights in LDS) + f32 residual -> f32 ----------------
template <int OT>
__global__ __launch_bounds__(256) void conv1x1_f_kernel(
    const bf16* __restrict__ in, const float* __restrict__ w,
    const float* __restrict__ res, float* __restrict__ out,
    int Cin, int Cout) {
  extern __shared__ float wlds[];   // [OT][Cin]
  int bb = blockIdx.z;
  int o0 = blockIdx.y * OT;
  int n  = blockIdx.x * blockDim.x + threadIdx.x;

  for (int i = threadIdx.x; i < OT * Cin; i += blockDim.x) {
    int oi = i / Cin, c = i % Cin;
    wlds[i] = (o0 + oi < Cout) ? w[(size_t)(o0 + oi) * Cin + c] : 0.f;
  }
  __syncthreads();

  const bf16* ip = in + ((size_t)bb * Cin) * NPIX + n;
  float acc[OT];
#pragma unroll
  for (int i = 0; i < OT; ++i) acc[i] = 0.f;

  for (int c = 0; c < Cin; ++c) {
    float xv = b2f(ip[(size_t)c * NPIX]);
#pragma unroll
    for (int i = 0; i < OT; ++i) acc[i] += wlds[i * Cin + c] * xv;
  }

#pragma unroll
  for (int i = 0; i < OT; ++i) {
    int o = o0 + i;
    if (o < Cout) {
      size_t off = ((size_t)bb * Cout + o) * NPIX + n;
      out[off] = acc[i] + res[off];
    }
  }
}

// ---------------- per-channel 1/max(||row||,1e-12) for q and k ----------------
__global__ __launch_bounds__(256) void rnorm_kernel(
    const bf16* __restrict__ qkvg, float* __restrict__ rn) {
  int bid = blockIdx.x;
  int bb = bid / 384, ci = bid % 384;
  int ch = (ci < 192) ? ci : (ci + 192);   // q at 0..191, k at 384..575
  const bf16* p = qkvg + ((size_t)bb * OQKV + ch) * NPIX;
  float s = 0.f;
  for (int i = threadIdx.x; i < NPIX; i += blockDim.x) {
    float v = b2f(p[i]); s += v * v;
  }
  for (int off = 32; off; off >>= 1) s += __shfl_down(s, off);
  __shared__ float red[4];
  int wave = threadIdx.x >> 6, lane = threadIdx.x & 63;
  if (lane == 0) red[wave] = s;
  __syncthreads();
  if (threadIdx.x == 0) {
    float t = red[0] + red[1] + red[2] + red[3];
    rn[bid] = 1.f / fmaxf(sqrtf(t), 1e-12f);
  }
}

// ---------------- attention logits + softmax ----------------
__global__ __launch_bounds__(256) void attn_kernel(
    const bf16* __restrict__ qkvg, const float* __restrict__ rn,
    const float* __restrict__ temp, float* __restrict__ attn) {
  int bid = blockIdx.x;
  int bb = bid / 192, g = bid % 192;
  int h = g / HDDIM, c = g % HDDIM;
  const bf16* qrow  = qkvg + ((size_t)bb * OQKV + g) * NPIX;
  const bf16* kbase = qkvg + ((size_t)bb * OQKV + 384 + h * HDDIM) * NPIX;
  int wave = threadIdx.x >> 6, lane = threadIdx.x & 63;
  __shared__ float dots[HDDIM];
  for (int d = wave; d < HDDIM; d += 4) {
    const bf16* krow = kbase + (size_t)d * NPIX;
    float s = 0.f;
    for (int i = lane; i < NPIX; i += 64) s += b2f(qrow[i]) * b2f(krow[i]);
    for (int off = 32; off; off >>= 1) s += __shfl_down(s, off);
    if (lane == 0) dots[d] = s;
  }
  __syncthreads();
  if (threadIdx.x == 0) {
    float rq = rn[bb * 384 + g];
    float tp = temp[h];
    float l[HDDIM];
    float m = -1e30f;
    for (int d = 0; d < HDDIM; ++d) {
      float rk = rn[bb * 384 + 192 + h * HDDIM + d];
      float v = dots[d] * rq * rk * tp;
      l[d] = v;
      m = fmaxf(m, v);
    }
    float sum = 0.f;
    for (int d = 0; d < HDDIM; ++d) { float e = expf(l[d] - m); l[d] = e; sum += e; }
    float inv = 1.f / sum;
    float* arow = attn + ((size_t)(bb * NHEADS + h)) * HDDIM * HDDIM + c * HDDIM;
    for (int d = 0; d < HDDIM; ++d) arow[d] = l[d] * inv;
  }
}

// ---------------- out = (attn @ v) * sigmoid(gate) -> bf16 ----------------
__global__ __launch_bounds__(256) void attnout_kernel(
    const bf16* __restrict__ qkvg, const float* __restrict__ attn,
    bf16* __restrict__ out) {
  int n  = blockIdx.x * blockDim.x + threadIdx.x;
  int c  = blockIdx.y;
  int bh = blockIdx.z;
  int bb = bh >> 2, h = bh & 3;
  int g = h * HDDIM + c;
  __shared__ float a[HDDIM];
  if (threadIdx.x < HDDIM)
    a[threadIdx.x] = attn[((size_t)bh) * HDDIM * HDDIM + c * HDDIM + threadIdx.x];
  __syncthreads();
  const bf16* vbase = qkvg + ((size_t)bb * OQKV + 576 + h * HDDIM) * NPIX + n;
  float acc = 0.f;
#pragma unroll 8
  for (int d = 0; d < HDDIM; ++d) acc += a[d] * b2f(vbase[(size_t)d * NPIX]);
  float gate = b2f(qkvg[((size_t)bb * OQKV + 192 + g) * NPIX + n]);
  float sg = 1.f / (1.f + expf(-gate));
  out[((size_t)bb * CDIM + g) * NPIX + n] = f2b(acc * sg);
}

extern "C" void kernel_launch(void* const* d_in, const int* in_sizes, int n_in,
                              void* d_out, int out_size, void* d_ws, size_t ws_size,
                              hipStream_t stream) {
  const float* x        = (const float*)d_in[0];
  const float* ln1_w    = (const float*)d_in[1];
  const float* ln1_b    = (const float*)d_in[2];
  const float* qkv_w    = (const float*)d_in[3];
  const float* qkv_dw_w = (const float*)d_in[4];
  const float* temp     = (const float*)d_in[5];
  const float* proj_w   = (const float*)d_in[6];
  const float* ln2_w    = (const float*)d_in[7];
  const float* ln2_b    = (const float*)d_in[8];
  const float* ffn_in_w = (const float*)d_in[9];
  const float* ffn_dw_w = (const float*)d_in[10];
  const float* ffn_out_w= (const float*)d_in[11];
  float* out = (float*)d_out;

  const size_t NQKV_E = (size_t)BATCH * OQKV * NPIX;   // 50,331,648
  const size_t NS_E   = (size_t)BATCH * CDIM * NPIX;   // 12,582,912
  const size_t NG_E   = (size_t)BATCH * HIDDEN_ * NPIX;// 33,423,360

  // ws layout (~120.2 MiB total):
  //   A  [0,          96 MiB): qkvg (attn phase)  |  ln2-out (24 MiB) + gated (64 MiB) (ffn phase)
  //   B  [96 MiB,    120 MiB): ln1-out, later attnout-out
  //   RN, AT: small
  char* p = (char*)d_ws;
  bf16*  wsA  = (bf16*)p;                 p += NQKV_E * sizeof(bf16);
  bf16*  wsB  = (bf16*)p;                 p += NS_E * sizeof(bf16);
  float* wsRN = (float*)p;                p += 1536 * sizeof(float);
  float* wsAT = (float*)p;                p += 36864 * sizeof(float);
  bf16*  wsLN2 = wsA;                     // 24 MiB
  bf16*  wsG   = wsA + NS_E;              // gated, 64 MiB (offset 24 MiB)

  dim3 blk(256);

  // ---- attention branch ----
  ln_kernel<<<dim3((BATCH * NPIX + 255) / 256), blk, 0, stream>>>(x, ln1_w, ln1_b, wsB);

  fused_conv_dw_kernel<16, false><<<dim3(64, OQKV / 16, BATCH), blk, 0, stream>>>(
      wsB, qkv_w, qkv_dw_w, wsA, OQKV);

  rnorm_kernel<<<dim3(BATCH * 384), blk, 0, stream>>>(wsA, wsRN);

  attn_kernel<<<dim3(BATCH * CDIM), blk, 0, stream>>>(wsA, wsRN, temp, wsAT);

  attnout_kernel<<<dim3(NPIX / 256, HDDIM, BATCH * NHEADS), blk, 0, stream>>>(
      wsA, wsAT, wsB);

  conv1x1_f_kernel<16><<<dim3(NPIX / 256, CDIM / 16, BATCH), blk, 16 * CDIM * 4, stream>>>(
      wsB, proj_w, x, out, CDIM, CDIM);   // out = x1 (f32), lives in d_out

  // ---- ffn branch ----
  ln_kernel<<<dim3((BATCH * NPIX + 255) / 256), blk, 0, stream>>>(out, ln2_w, ln2_b, wsLN2);

  fused_conv_dw_kernel<10, true><<<dim3(64, HIDDEN_ / 10, BATCH), blk, 0, stream>>>(
      wsLN2, ffn_in_w, ffn_dw_w, wsG, OFFN);

  conv1x1_f_kernel<16><<<dim3(NPIX / 256, CDIM / 16, BATCH), blk, 16 * HIDDEN_ * 4, stream>>>(
      wsG, ffn_out_w, out, out, HIDDEN_, CDIM);  // += x1 residual (in-place per-thread)
}

// Round 5
// 4813.828 us; speedup vs baseline: 2.7880x; 2.7880x over previous
//
#include <hip/hip_runtime.h>
#include <hip/hip_bf16.h>
#include <math.h>

#define CDIM    192
#define NHEADS  4
#define HDDIM   48
#define HH      128
#define WW      128
#define NPIX    16384      // 128*128
#define OQKV    768
#define HIDDEN_ 510
#define OFFN    1020
#define LNEPS   1e-5f

typedef __hip_bfloat16 bf16;
typedef __attribute__((ext_vector_type(8))) short short8;
typedef __attribute__((ext_vector_type(4))) float f32x4;

__device__ __forceinline__ float b2f(bf16 v) { return __bfloat162float(v); }
__device__ __forceinline__ bf16  f2b(float v) { return __float2bfloat16(v); }
__device__ __forceinline__ unsigned short f2bbits(float v) {
  bf16 h = __float2bfloat16(v);
  return *(unsigned short*)&h;
}
__device__ __forceinline__ float us2f(unsigned short u) {
  union { unsigned int i; float f; } cv; cv.i = ((unsigned int)u) << 16; return cv.f;
}

// ---------------- LayerNorm over channels, per pixel. x:[C][N] f32 -> y:[N][C] bf16 ----------------
// grid: NPIX/64 blocks, 256 threads
__global__ __launch_bounds__(256) void ln_t_kernel(
    const float* __restrict__ x, const float* __restrict__ w,
    const float* __restrict__ b, bf16* __restrict__ y) {
  __shared__ float red[8][64];
  __shared__ float mu_s[64], rs_s[64];
  __shared__ unsigned short tile[64 * 194];   // [p][c] padded stride 194
  const int t = threadIdx.x;
  const int n0 = blockIdx.x * 64;
  const int p = t & 63, q = t >> 6;           // 4 channel-quarters

  float s = 0.f, ss = 0.f;
  for (int c = q * 48; c < q * 48 + 48; ++c) {
    float v = x[(size_t)c * NPIX + n0 + p];
    s += v; ss += v * v;
  }
  red[q][p] = s; red[4 + q][p] = ss;
  __syncthreads();
  if (t < 64) {
    float S  = red[0][t] + red[1][t] + red[2][t] + red[3][t];
    float SS = red[4][t] + red[5][t] + red[6][t] + red[7][t];
    float mu = S * (1.f / CDIM);
    float var = SS * (1.f / CDIM) - mu * mu;
    mu_s[t] = mu; rs_s[t] = rsqrtf(var + LNEPS);
  }
  __syncthreads();
  // compute normalized values into LDS tile (reads coalesced over p)
  for (int i = 0; i < 48; ++i) {
    int flat = i * 256 + t;          // = c*64 + p2
    int c = flat >> 6, p2 = flat & 63;
    float v = (x[(size_t)c * NPIX + n0 + p2] - mu_s[p2]) * rs_s[p2] * w[c] + b[c];
    tile[p2 * 194 + c] = f2bbits(v);
  }
  __syncthreads();
  // write [n][c] contiguous
  unsigned short* yo = (unsigned short*)y + (size_t)n0 * CDIM;
  for (int i = 0; i < 48; ++i) {
    int flat = i * 256 + t;          // = pp*192 + cc
    int pp = flat / 192, cc = flat - pp * 192;
    yo[flat] = tile[pp * 194 + cc];
  }
}

// ---------------- MFMA GEMM: out[m][n] = sum_k W[m][k]*act[k][n] ----------------
// act: BT ? [K][NPIX] (channel-major) : [NPIX][K] (pixel-major)
// BM=BN=128, BK=32, 256 threads (4 waves, 2x2), per-wave 64x64 (4x4 frags)
// F32OUT: out f32 = acc + res ; else out bf16
template <bool BT, bool F32OUT>
__global__ __launch_bounds__(256) void gemm_kernel(
    const bf16* __restrict__ Bact, const float* __restrict__ W,
    const float* __restrict__ res, void* __restrict__ outp,
    int M, int K) {
  __shared__ __align__(16) unsigned short sA[128 * 40];  // [m][k] pad->40
  __shared__ __align__(16) unsigned short sB[128 * 40];  // [n][k] pad->40
  const int t = threadIdx.x;
  const int lane = t & 63;
  const int wave = t >> 6;
  const int wm = wave >> 1, wn = wave & 1;
  const int l15 = lane & 15, lk = lane >> 4;
  const int n0 = blockIdx.x * 128;
  const int m0 = blockIdx.y * 128;

  f32x4 acc[4][4];
#pragma unroll
  for (int i = 0; i < 4; ++i)
#pragma unroll
    for (int j = 0; j < 4; ++j) acc[i][j] = (f32x4){0.f, 0.f, 0.f, 0.f};

  const int Ksteps = (K + 31) >> 5;
  for (int ks = 0; ks < Ksteps; ++ks) {
    const int k0 = ks << 5;
    __syncthreads();
    // ---- stage A (weights f32 -> bf16): thread: m=t>>1, half=t&1 handles 16 k
    {
      const int m = t >> 1, half = t & 1;
      const int gm = m0 + m;
      const int kb = k0 + half * 16;
      short8 v0, v1;
#pragma unroll
      for (int j = 0; j < 8; ++j) {
        float a0 = (gm < M && kb + j < K)     ? W[(size_t)gm * K + kb + j]     : 0.f;
        float a1 = (gm < M && kb + 8 + j < K) ? W[(size_t)gm * K + kb + 8 + j] : 0.f;
        v0[j] = (short)f2bbits(a0);
        v1[j] = (short)f2bbits(a1);
      }
      *(short8*)&sA[m * 40 + half * 16]     = v0;
      *(short8*)&sA[m * 40 + half * 16 + 8] = v1;
    }
    // ---- stage B
    if (!BT) {
      // act [NPIX][K], K multiple of 32 for NT users (K=192)
      const int n = t >> 1, half = t & 1;
      const short8* src = (const short8*)(Bact + (size_t)(n0 + n) * K + k0 + half * 16);
      short8 v0 = src[0];
      short8 v1 = src[1];
      *(short8*)&sB[n * 40 + half * 16]     = v0;
      *(short8*)&sB[n * 40 + half * 16 + 8] = v1;
    } else {
      // act [K][NPIX]; transpose-stage. thread: k=t>>3, part=t&7 handles 16 n
      const int k = t >> 3, part = t & 7;
      const int gk = k0 + k;
      short8 v0 = {}, v1 = {};
      if (gk < K) {
        const short8* src = (const short8*)(Bact + (size_t)gk * NPIX + n0 + part * 16);
        v0 = src[0]; v1 = src[1];
      }
#pragma unroll
      for (int j = 0; j < 8; ++j) {
        sB[(part * 16 + j) * 40 + k]       = (unsigned short)v0[j];
        sB[(part * 16 + 8 + j) * 40 + k]   = (unsigned short)v1[j];
      }
    }
    __syncthreads();
    // ---- fragments + MFMA
    short8 af[4], bf_[4];
#pragma unroll
    for (int mf = 0; mf < 4; ++mf)
      af[mf] = *(const short8*)&sA[(wm * 64 + mf * 16 + l15) * 40 + lk * 8];
#pragma unroll
    for (int nf = 0; nf < 4; ++nf)
      bf_[nf] = *(const short8*)&sB[(wn * 64 + nf * 16 + l15) * 40 + lk * 8];
#pragma unroll
    for (int mf = 0; mf < 4; ++mf)
#pragma unroll
      for (int nf = 0; nf < 4; ++nf)
        acc[mf][nf] = __builtin_amdgcn_mfma_f32_16x16x32_bf16(
            af[mf], bf_[nf], acc[mf][nf], 0, 0, 0);
  }

  // ---- epilogue: D col = lane&15, row = (lane>>4)*4 + reg
#pragma unroll
  for (int mf = 0; mf < 4; ++mf) {
#pragma unroll
    for (int nf = 0; nf < 4; ++nf) {
#pragma unroll
      for (int r = 0; r < 4; ++r) {
        int m = m0 + wm * 64 + mf * 16 + lk * 4 + r;
        int n = n0 + wn * 64 + nf * 16 + l15;
        if (m < M) {
          size_t off = (size_t)m * NPIX + n;
          if (F32OUT) ((float*)outp)[off] = acc[mf][nf][r] + res[off];
          else        ((bf16*)outp)[off]  = f2b(acc[mf][nf][r]);
        }
      }
    }
  }
}

// ---------------- depthwise 3x3, zero pad 1, [C][N] bf16 -> [C][N] bf16 (per image) ----------------
__global__ __launch_bounds__(256) void dwconv_kernel(
    const bf16* __restrict__ in, const float* __restrict__ w,
    bf16* __restrict__ out, int Ch) {
  size_t idx = (size_t)blockIdx.x * blockDim.x + threadIdx.x;
  if (idx >= (size_t)Ch * NPIX) return;
  int n = (int)(idx % NPIX);
  int ch = (int)(idx / NPIX);
  int y = n / WW, x = n % WW;
  const bf16* ip = in + (size_t)ch * NPIX;
  const float* wp = w + (size_t)ch * 9;
  float acc = 0.f;
#pragma unroll
  for (int ky = 0; ky < 3; ++ky) {
    int yy = y + ky - 1;
    if (yy < 0 || yy >= HH) continue;
#pragma unroll
    for (int kx = 0; kx < 3; ++kx) {
      int xx = x + kx - 1;
      if (xx < 0 || xx >= WW) continue;
      acc += wp[ky * 3 + kx] * b2f(ip[yy * WW + xx]);
    }
  }
  out[idx] = f2b(acc);
}

// ---------------- fused FFN dwconv3x3 + gelu(x1)*x2 (per image) ----------------
__global__ __launch_bounds__(256) void dwgelu_kernel(
    const bf16* __restrict__ in, const float* __restrict__ w,
    bf16* __restrict__ out) {
  size_t idx = (size_t)blockIdx.x * blockDim.x + threadIdx.x;
  if (idx >= (size_t)HIDDEN_ * NPIX) return;
  int n = (int)(idx % NPIX);
  int ch = (int)(idx / NPIX);
  int y = n / WW, x = n % WW;
  const bf16* ip1 = in + (size_t)ch * NPIX;
  const bf16* ip2 = ip1 + (size_t)HIDDEN_ * NPIX;
  const float* wp1 = w + (size_t)ch * 9;
  const float* wp2 = w + (size_t)(ch + HIDDEN_) * 9;
  float a1 = 0.f, a2 = 0.f;
#pragma unroll
  for (int ky = 0; ky < 3; ++ky) {
    int yy = y + ky - 1;
    if (yy < 0 || yy >= HH) continue;
#pragma unroll
    for (int kx = 0; kx < 3; ++kx) {
      int xx = x + kx - 1;
      if (xx < 0 || xx >= WW) continue;
      int o = yy * WW + kx + xx - kx;  // = yy*WW + xx
      a1 += wp1[ky * 3 + kx] * b2f(ip1[o]);
      a2 += wp2[ky * 3 + kx] * b2f(ip2[o]);
    }
  }
  float ge = 0.5f * a1 * (1.f + erff(a1 * 0.70710678118f));
  out[idx] = f2b(ge * a2);
}

// ---------------- per-channel 1/max(||row||,1e-12) for q and k (per image) ----------------
__global__ __launch_bounds__(256) void rnorm_kernel(
    const bf16* __restrict__ qkvg, float* __restrict__ rn) {
  int ci = blockIdx.x;                        // 0..383
  int ch = (ci < 192) ? ci : (ci + 192);      // q at 0..191, k at 384..575
  const bf16* p = qkvg + (size_t)ch * NPIX;
  float s = 0.f;
  for (int i = threadIdx.x; i < NPIX; i += blockDim.x) {
    float v = b2f(p[i]); s += v * v;
  }
  for (int off = 32; off; off >>= 1) s += __shfl_down(s, off);
  __shared__ float red[4];
  int wave = threadIdx.x >> 6, lane = threadIdx.x & 63;
  if (lane == 0) red[wave] = s;
  __syncthreads();
  if (threadIdx.x == 0) {
    float tsum = red[0] + red[1] + red[2] + red[3];
    rn[ci] = 1.f / fmaxf(sqrtf(tsum), 1e-12f);
  }
}

// ---------------- attention logits + softmax (per image) ----------------
// block per (h, c): blockIdx.x = h*48 + c ; 256 threads (4 waves)
__global__ __launch_bounds__(256) void attn_kernel(
    const bf16* __restrict__ qkvg, const float* __restrict__ rn,
    const float* __restrict__ temp, float* __restrict__ attn) {
  int g = blockIdx.x;                 // 0..191
  int h = g / HDDIM, c = g % HDDIM;
  const bf16* qrow  = qkvg + (size_t)g * NPIX;
  const bf16* kbase = qkvg + (size_t)(384 + h * HDDIM) * NPIX;
  int wave = threadIdx.x >> 6, lane = threadIdx.x & 63;
  __shared__ float dots[HDDIM];
  for (int d = wave; d < HDDIM; d += 4) {
    const bf16* krow = kbase + (size_t)d * NPIX;
    float s = 0.f;
    for (int i = lane; i < NPIX; i += 64) s += b2f(qrow[i]) * b2f(krow[i]);
    for (int off = 32; off; off >>= 1) s += __shfl_down(s, off);
    if (lane == 0) dots[d] = s;
  }
  __syncthreads();
  if (threadIdx.x == 0) {
    float rq = rn[g];
    float tp = temp[h];
    float l[HDDIM];
    float m = -1e30f;
    for (int d = 0; d < HDDIM; ++d) {
      float rk = rn[192 + h * HDDIM + d];
      float v = dots[d] * rq * rk * tp;
      l[d] = v;
      m = fmaxf(m, v);
    }
    float sum = 0.f;
    for (int d = 0; d < HDDIM; ++d) { float e = expf(l[d] - m); l[d] = e; sum += e; }
    float inv = 1.f / sum;
    float* arow = attn + (size_t)(h * HDDIM + c) * HDDIM;
    for (int d = 0; d < HDDIM; ++d) arow[d] = l[d] * inv;
  }
}

// ---------------- out = (attn @ v) * sigmoid(gate) -> [C][N] bf16 (per image) ----------------
// grid: (NPIX/256, 48, 4)
__global__ __launch_bounds__(256) void attnout_kernel(
    const bf16* __restrict__ qkvg, const float* __restrict__ attn,
    bf16* __restrict__ out) {
  int n = blockIdx.x * blockDim.x + threadIdx.x;
  int c = blockIdx.y;
  int h = blockIdx.z;
  int g = h * HDDIM + c;
  __shared__ float a[HDDIM];
  if (threadIdx.x < HDDIM)
    a[threadIdx.x] = attn[(size_t)(h * HDDIM + c) * HDDIM + threadIdx.x];
  __syncthreads();
  const bf16* vbase = qkvg + (size_t)(576 + h * HDDIM) * NPIX + n;
  float acc = 0.f;
#pragma unroll 8
  for (int d = 0; d < HDDIM; ++d) acc += a[d] * b2f(vbase[(size_t)d * NPIX]);
  float gate = b2f(qkvg[(size_t)(192 + g) * NPIX + n]);
  float sg = 1.f / (1.f + expf(-gate));
  out[(size_t)g * NPIX + n] = f2b(acc * sg);
}

extern "C" void kernel_launch(void* const* d_in, const int* in_sizes, int n_in,
                              void* d_out, int out_size, void* d_ws, size_t ws_size,
                              hipStream_t stream) {
  const float* x        = (const float*)d_in[0];
  const float* ln1_w    = (const float*)d_in[1];
  const float* ln1_b    = (const float*)d_in[2];
  const float* qkv_w    = (const float*)d_in[3];
  const float* qkv_dw_w = (const float*)d_in[4];
  const float* temp     = (const float*)d_in[5];
  const float* proj_w   = (const float*)d_in[6];
  const float* ln2_w    = (const float*)d_in[7];
  const float* ln2_b    = (const float*)d_in[8];
  const float* ffn_in_w = (const float*)d_in[9];
  const float* ffn_dw_w = (const float*)d_in[10];
  const float* ffn_out_w= (const float*)d_in[11];
  float* out = (float*)d_out;

  // per-image workspace (~84 MiB total)
  char* p = (char*)d_ws;
  bf16*  lnout   = (bf16*)p;  p += (size_t)NPIX * CDIM    * sizeof(bf16);  //  6 MiB
  bf16*  convout = (bf16*)p;  p += (size_t)NPIX * OFFN    * sizeof(bf16);  // 32 MiB
  bf16*  qkvg    = (bf16*)p;  p += (size_t)NPIX * OQKV    * sizeof(bf16);  // 24 MiB
  bf16*  gated   = (bf16*)p;  p += (size_t)NPIX * HIDDEN_ * sizeof(bf16);  // 16 MiB
  bf16*  attout  = (bf16*)p;  p += (size_t)NPIX * CDIM    * sizeof(bf16);  //  6 MiB
  float* rn      = (float*)p; p += 384 * sizeof(float);
  float* attnm   = (float*)p; p += NHEADS * HDDIM * HDDIM * sizeof(float);

  dim3 blk(256);

  for (int img = 0; img < 4; ++img) {
    const float* x_i = x + (size_t)img * CDIM * NPIX;
    float* out_i = out + (size_t)img * CDIM * NPIX;

    // ---- attention branch ----
    ln_t_kernel<<<dim3(NPIX / 64), blk, 0, stream>>>(x_i, ln1_w, ln1_b, lnout);

    gemm_kernel<false, false><<<dim3(128, OQKV / 128), blk, 0, stream>>>(
        lnout, qkv_w, nullptr, convout, OQKV, CDIM);

    dwconv_kernel<<<dim3((OQKV * NPIX) / 256), blk, 0, stream>>>(
        convout, qkv_dw_w, qkvg, OQKV);

    rnorm_kernel<<<dim3(384), blk, 0, stream>>>(qkvg, rn);

    attn_kernel<<<dim3(CDIM), blk, 0, stream>>>(qkvg, rn, temp, attnm);

    attnout_kernel<<<dim3(NPIX / 256, HDDIM, NHEADS), blk, 0, stream>>>(
        qkvg, attnm, attout);

    gemm_kernel<true, true><<<dim3(128, 2), blk, 0, stream>>>(
        attout, proj_w, x_i, out_i, CDIM, CDIM);       // x1 -> d_out

    // ---- ffn branch ----
    ln_t_kernel<<<dim3(NPIX / 64), blk, 0, stream>>>(out_i, ln2_w, ln2_b, lnout);

    gemm_kernel<false, false><<<dim3(128, 8), blk, 0, stream>>>(
        lnout, ffn_in_w, nullptr, convout, OFFN, CDIM);

    dwgelu_kernel<<<dim3((HIDDEN_ * NPIX + 255) / 256), blk, 0, stream>>>(
        convout, ffn_dw_w, gated);

    gemm_kernel<true, true><<<dim3(128, 2), blk, 0, stream>>>(
        gated, ffn_out_w, out_i, out_i, CDIM, HIDDEN_); // final = x1 + conv
  }
}

// Round 6
// 1910.883 us; speedup vs baseline: 7.0235x; 2.5192x over previous
//
#include <hip/hip_runtime.h>
#include <hip/hip_bf16.h>
#include <math.h>

#define CDIM    192
#define NHEADS  4
#define HDDIM   48
#define HH      128
#define WW      128
#define NPIX    16384      // 128*128
#define OQKV    768
#define HIDDEN_ 510
#define OFFN    1020
#define LNEPS   1e-5f
#define KSPLIT  64

typedef __hip_bfloat16 bf16;
typedef __attribute__((ext_vector_type(8))) short short8;
typedef __attribute__((ext_vector_type(4))) float f32x4;

__device__ __forceinline__ float b2f(bf16 v) { return __bfloat162float(v); }
__device__ __forceinline__ bf16  f2b(float v) { return __float2bfloat16(v); }
__device__ __forceinline__ unsigned short f2bbits(float v) {
  bf16 h = __float2bfloat16(v);
  return *(unsigned short*)&h;
}

// ---------------- LayerNorm over channels, per pixel. x:[C][N] f32 -> y:[N][C] bf16 ----------------
__global__ __launch_bounds__(256) void ln_t_kernel(
    const float* __restrict__ x, const float* __restrict__ w,
    const float* __restrict__ b, bf16* __restrict__ y) {
  __shared__ float red[8][64];
  __shared__ float mu_s[64], rs_s[64];
  __shared__ unsigned short tile[64 * 194];
  const int t = threadIdx.x;
  const int n0 = blockIdx.x * 64;
  const int p = t & 63, q = t >> 6;

  float s = 0.f, ss = 0.f;
  for (int c = q * 48; c < q * 48 + 48; ++c) {
    float v = x[(size_t)c * NPIX + n0 + p];
    s += v; ss += v * v;
  }
  red[q][p] = s; red[4 + q][p] = ss;
  __syncthreads();
  if (t < 64) {
    float S  = red[0][t] + red[1][t] + red[2][t] + red[3][t];
    float SS = red[4][t] + red[5][t] + red[6][t] + red[7][t];
    float mu = S * (1.f / CDIM);
    float var = SS * (1.f / CDIM) - mu * mu;
    mu_s[t] = mu; rs_s[t] = rsqrtf(var + LNEPS);
  }
  __syncthreads();
  for (int i = 0; i < 48; ++i) {
    int flat = i * 256 + t;
    int c = flat >> 6, p2 = flat & 63;
    float v = (x[(size_t)c * NPIX + n0 + p2] - mu_s[p2]) * rs_s[p2] * w[c] + b[c];
    tile[p2 * 194 + c] = f2bbits(v);
  }
  __syncthreads();
  unsigned short* yo = (unsigned short*)y + (size_t)n0 * CDIM;
  for (int i = 0; i < 48; ++i) {
    int flat = i * 256 + t;
    int pp = flat / 192, cc = flat - pp * 192;
    yo[flat] = tile[pp * 194 + cc];
  }
}

// ---------------- MFMA GEMM: out[m][n] = sum_k W[m][k]*act[k][n] ----------------
template <bool BT, bool F32OUT>
__global__ __launch_bounds__(256) void gemm_kernel(
    const bf16* __restrict__ Bact, const float* __restrict__ W,
    const float* __restrict__ res, void* __restrict__ outp,
    int M, int K) {
  __shared__ __align__(16) unsigned short sA[128 * 40];
  __shared__ __align__(16) unsigned short sB[128 * 40];
  const int t = threadIdx.x;
  const int lane = t & 63;
  const int wave = t >> 6;
  const int wm = wave >> 1, wn = wave & 1;
  const int l15 = lane & 15, lk = lane >> 4;
  const int n0 = blockIdx.x * 128;
  const int m0 = blockIdx.y * 128;

  f32x4 acc[4][4];
#pragma unroll
  for (int i = 0; i < 4; ++i)
#pragma unroll
    for (int j = 0; j < 4; ++j) acc[i][j] = (f32x4){0.f, 0.f, 0.f, 0.f};

  const int Ksteps = (K + 31) >> 5;
  for (int ks = 0; ks < Ksteps; ++ks) {
    const int k0 = ks << 5;
    __syncthreads();
    {
      const int m = t >> 1, half = t & 1;
      const int gm = m0 + m;
      const int kb = k0 + half * 16;
      short8 v0, v1;
#pragma unroll
      for (int j = 0; j < 8; ++j) {
        float a0 = (gm < M && kb + j < K)     ? W[(size_t)gm * K + kb + j]     : 0.f;
        float a1 = (gm < M && kb + 8 + j < K) ? W[(size_t)gm * K + kb + 8 + j] : 0.f;
        v0[j] = (short)f2bbits(a0);
        v1[j] = (short)f2bbits(a1);
      }
      *(short8*)&sA[m * 40 + half * 16]     = v0;
      *(short8*)&sA[m * 40 + half * 16 + 8] = v1;
    }
    if (!BT) {
      const int n = t >> 1, half = t & 1;
      const short8* src = (const short8*)(Bact + (size_t)(n0 + n) * K + k0 + half * 16);
      short8 v0 = src[0];
      short8 v1 = src[1];
      *(short8*)&sB[n * 40 + half * 16]     = v0;
      *(short8*)&sB[n * 40 + half * 16 + 8] = v1;
    } else {
      const int k = t >> 3, part = t & 7;
      const int gk = k0 + k;
      short8 v0 = {}, v1 = {};
      if (gk < K) {
        const short8* src = (const short8*)(Bact + (size_t)gk * NPIX + n0 + part * 16);
        v0 = src[0]; v1 = src[1];
      }
#pragma unroll
      for (int j = 0; j < 8; ++j) {
        sB[(part * 16 + j) * 40 + k]       = (unsigned short)v0[j];
        sB[(part * 16 + 8 + j) * 40 + k]   = (unsigned short)v1[j];
      }
    }
    __syncthreads();
    short8 af[4], bf_[4];
#pragma unroll
    for (int mf = 0; mf < 4; ++mf)
      af[mf] = *(const short8*)&sA[(wm * 64 + mf * 16 + l15) * 40 + lk * 8];
#pragma unroll
    for (int nf = 0; nf < 4; ++nf)
      bf_[nf] = *(const short8*)&sB[(wn * 64 + nf * 16 + l15) * 40 + lk * 8];
#pragma unroll
    for (int mf = 0; mf < 4; ++mf)
#pragma unroll
      for (int nf = 0; nf < 4; ++nf)
        acc[mf][nf] = __builtin_amdgcn_mfma_f32_16x16x32_bf16(
            af[mf], bf_[nf], acc[mf][nf], 0, 0, 0);
  }

#pragma unroll
  for (int mf = 0; mf < 4; ++mf) {
#pragma unroll
    for (int nf = 0; nf < 4; ++nf) {
#pragma unroll
      for (int r = 0; r < 4; ++r) {
        int m = m0 + wm * 64 + mf * 16 + lk * 4 + r;
        int n = n0 + wn * 64 + nf * 16 + l15;
        if (m < M) {
          size_t off = (size_t)m * NPIX + n;
          if (F32OUT) ((float*)outp)[off] = acc[mf][nf][r] + res[off];
          else        ((bf16*)outp)[off]  = f2b(acc[mf][nf][r]);
        }
      }
    }
  }
}

// ---------------- depthwise 3x3, zero pad 1, [C][N] bf16 -> [C][N] bf16 ----------------
__global__ __launch_bounds__(256) void dwconv_kernel(
    const bf16* __restrict__ in, const float* __restrict__ w,
    bf16* __restrict__ out, int Ch) {
  size_t idx = (size_t)blockIdx.x * blockDim.x + threadIdx.x;
  if (idx >= (size_t)Ch * NPIX) return;
  int n = (int)(idx % NPIX);
  int ch = (int)(idx / NPIX);
  int y = n / WW, x = n % WW;
  const bf16* ip = in + (size_t)ch * NPIX;
  const float* wp = w + (size_t)ch * 9;
  float acc = 0.f;
#pragma unroll
  for (int ky = 0; ky < 3; ++ky) {
    int yy = y + ky - 1;
    if (yy < 0 || yy >= HH) continue;
#pragma unroll
    for (int kx = 0; kx < 3; ++kx) {
      int xx = x + kx - 1;
      if (xx < 0 || xx >= WW) continue;
      acc += wp[ky * 3 + kx] * b2f(ip[yy * WW + xx]);
    }
  }
  out[idx] = f2b(acc);
}

// ---------------- fused FFN dwconv3x3 + gelu(x1)*x2 ----------------
__global__ __launch_bounds__(256) void dwgelu_kernel(
    const bf16* __restrict__ in, const float* __restrict__ w,
    bf16* __restrict__ out) {
  size_t idx = (size_t)blockIdx.x * blockDim.x + threadIdx.x;
  if (idx >= (size_t)HIDDEN_ * NPIX) return;
  int n = (int)(idx % NPIX);
  int ch = (int)(idx / NPIX);
  int y = n / WW, x = n % WW;
  const bf16* ip1 = in + (size_t)ch * NPIX;
  const bf16* ip2 = ip1 + (size_t)HIDDEN_ * NPIX;
  const float* wp1 = w + (size_t)ch * 9;
  const float* wp2 = w + (size_t)(ch + HIDDEN_) * 9;
  float a1 = 0.f, a2 = 0.f;
#pragma unroll
  for (int ky = 0; ky < 3; ++ky) {
    int yy = y + ky - 1;
    if (yy < 0 || yy >= HH) continue;
#pragma unroll
    for (int kx = 0; kx < 3; ++kx) {
      int xx = x + kx - 1;
      if (xx < 0 || xx >= WW) continue;
      int o = yy * WW + xx;
      a1 += wp1[ky * 3 + kx] * b2f(ip1[o]);
      a2 += wp2[ky * 3 + kx] * b2f(ip2[o]);
    }
  }
  float ge = 0.5f * a1 * (1.f + erff(a1 * 0.70710678118f));
  out[idx] = f2b(ge * a2);
}

// ---------------- per-channel 1/max(||row||,1e-12) for q and k ----------------
__global__ __launch_bounds__(256) void rnorm_kernel(
    const bf16* __restrict__ qkvg, float* __restrict__ rn) {
  int ci = blockIdx.x;
  int ch = (ci < 192) ? ci : (ci + 192);
  const bf16* p = qkvg + (size_t)ch * NPIX;
  float s = 0.f;
  for (int i = threadIdx.x; i < NPIX; i += blockDim.x) {
    float v = b2f(p[i]); s += v * v;
  }
  for (int off = 32; off; off >>= 1) s += __shfl_down(s, off);
  __shared__ float red[4];
  int wave = threadIdx.x >> 6, lane = threadIdx.x & 63;
  if (lane == 0) red[wave] = s;
  __syncthreads();
  if (threadIdx.x == 0) {
    float tsum = red[0] + red[1] + red[2] + red[3];
    rn[ci] = 1.f / fmaxf(sqrtf(tsum), 1e-12f);
  }
}

// ---------------- attention logits via split-K MFMA ----------------
// grid (KSPLIT, NHEADS), block 64 (1 wave). part[ks][h][48*48] f32.
// L[c][d] = sum_n q[c][n] * k[d][n]
__global__ __launch_bounds__(64) void attn_logits_kernel(
    const bf16* __restrict__ qkvg, float* __restrict__ part) {
  const int ks = blockIdx.x, h = blockIdx.y;
  const int lane = threadIdx.x;
  const int l15 = lane & 15, lk = lane >> 4;
  const bf16* qbase = qkvg + (size_t)(h * HDDIM) * NPIX;
  const bf16* kbase = qkvg + (size_t)(384 + h * HDDIM) * NPIX;

  f32x4 acc[3][3];
#pragma unroll
  for (int i = 0; i < 3; ++i)
#pragma unroll
    for (int j = 0; j < 3; ++j) acc[i][j] = (f32x4){0.f, 0.f, 0.f, 0.f};

  const int n_start = ks * (NPIX / KSPLIT);     // 256-pixel chunk
  for (int n0 = n_start; n0 < n_start + NPIX / KSPLIT; n0 += 32) {
    short8 af[3], bfr[3];
#pragma unroll
    for (int i = 0; i < 3; ++i)
      af[i] = *(const short8*)(qbase + (size_t)(i * 16 + l15) * NPIX + n0 + lk * 8);
#pragma unroll
    for (int j = 0; j < 3; ++j)
      bfr[j] = *(const short8*)(kbase + (size_t)(j * 16 + l15) * NPIX + n0 + lk * 8);
#pragma unroll
    for (int i = 0; i < 3; ++i)
#pragma unroll
      for (int j = 0; j < 3; ++j)
        acc[i][j] = __builtin_amdgcn_mfma_f32_16x16x32_bf16(af[i], bfr[j], acc[i][j], 0, 0, 0);
  }

  float* pp = part + ((size_t)(ks * NHEADS + h)) * (HDDIM * HDDIM);
#pragma unroll
  for (int i = 0; i < 3; ++i)
#pragma unroll
    for (int j = 0; j < 3; ++j)
#pragma unroll
      for (int r = 0; r < 4; ++r) {
        int row = i * 16 + lk * 4 + r;     // c (q channel)
        int col = j * 16 + l15;            // d (k channel)
        pp[row * HDDIM + col] = acc[i][j][r];
      }
}

// ---------------- reduce partials + scale + softmax ----------------
// grid 192 = h*48 + c, block 64 (1 wave; lanes 0..47 active)
__global__ __launch_bounds__(64) void attn_softmax_kernel(
    const float* __restrict__ part, const float* __restrict__ rn,
    const float* __restrict__ temp, float* __restrict__ attn) {
  int g = blockIdx.x;
  int h = g / HDDIM, c = g % HDDIM;
  int d = threadIdx.x;
  float v = 0.f;
  if (d < HDDIM) {
    for (int ks = 0; ks < KSPLIT; ++ks)
      v += part[((size_t)(ks * NHEADS + h)) * (HDDIM * HDDIM) + c * HDDIM + d];
    v *= rn[g] * rn[192 + h * HDDIM + d] * temp[h];
  }
  float lv = (d < HDDIM) ? v : -1e30f;
  float m = lv;
  for (int off = 32; off; off >>= 1) m = fmaxf(m, __shfl_xor(m, off));
  float e = (d < HDDIM) ? expf(lv - m) : 0.f;
  float s = e;
  for (int off = 32; off; off >>= 1) s += __shfl_xor(s, off);
  if (d < HDDIM) attn[(size_t)g * HDDIM + d] = e / s;
}

// ---------------- out = (attn @ v) * sigmoid(gate) -> [C][N] bf16 ----------------
__global__ __launch_bounds__(256) void attnout_kernel(
    const bf16* __restrict__ qkvg, const float* __restrict__ attn,
    bf16* __restrict__ out) {
  int n = blockIdx.x * blockDim.x + threadIdx.x;
  int c = blockIdx.y;
  int h = blockIdx.z;
  int g = h * HDDIM + c;
  __shared__ float a[HDDIM];
  if (threadIdx.x < HDDIM)
    a[threadIdx.x] = attn[(size_t)(h * HDDIM + c) * HDDIM + threadIdx.x];
  __syncthreads();
  const bf16* vbase = qkvg + (size_t)(576 + h * HDDIM) * NPIX + n;
  float acc = 0.f;
#pragma unroll 8
  for (int d = 0; d < HDDIM; ++d) acc += a[d] * b2f(vbase[(size_t)d * NPIX]);
  float gate = b2f(qkvg[(size_t)(192 + g) * NPIX + n]);
  float sg = 1.f / (1.f + expf(-gate));
  out[(size_t)g * NPIX + n] = f2b(acc * sg);
}

extern "C" void kernel_launch(void* const* d_in, const int* in_sizes, int n_in,
                              void* d_out, int out_size, void* d_ws, size_t ws_size,
                              hipStream_t stream) {
  const float* x        = (const float*)d_in[0];
  const float* ln1_w    = (const float*)d_in[1];
  const float* ln1_b    = (const float*)d_in[2];
  const float* qkv_w    = (const float*)d_in[3];
  const float* qkv_dw_w = (const float*)d_in[4];
  const float* temp     = (const float*)d_in[5];
  const float* proj_w   = (const float*)d_in[6];
  const float* ln2_w    = (const float*)d_in[7];
  const float* ln2_b    = (const float*)d_in[8];
  const float* ffn_in_w = (const float*)d_in[9];
  const float* ffn_dw_w = (const float*)d_in[10];
  const float* ffn_out_w= (const float*)d_in[11];
  float* out = (float*)d_out;

  // per-image workspace (~87 MiB total)
  char* p = (char*)d_ws;
  bf16*  lnout   = (bf16*)p;  p += (size_t)NPIX * CDIM    * sizeof(bf16);  //  6 MiB
  bf16*  convout = (bf16*)p;  p += (size_t)NPIX * OFFN    * sizeof(bf16);  // 32 MiB
  bf16*  qkvg    = (bf16*)p;  p += (size_t)NPIX * OQKV    * sizeof(bf16);  // 24 MiB
  bf16*  gated   = (bf16*)p;  p += (size_t)NPIX * HIDDEN_ * sizeof(bf16);  // 16 MiB
  bf16*  attout  = (bf16*)p;  p += (size_t)NPIX * CDIM    * sizeof(bf16);  //  6 MiB
  float* rn      = (float*)p; p += 384 * sizeof(float);
  float* attnm   = (float*)p; p += NHEADS * HDDIM * HDDIM * sizeof(float);
  float* partial = (float*)p; p += (size_t)KSPLIT * NHEADS * HDDIM * HDDIM * sizeof(float); // 2.4 MiB

  dim3 blk(256);

  for (int img = 0; img < 4; ++img) {
    const float* x_i = x + (size_t)img * CDIM * NPIX;
    float* out_i = out + (size_t)img * CDIM * NPIX;

    // ---- attention branch ----
    ln_t_kernel<<<dim3(NPIX / 64), blk, 0, stream>>>(x_i, ln1_w, ln1_b, lnout);

    gemm_kernel<false, false><<<dim3(128, OQKV / 128), blk, 0, stream>>>(
        lnout, qkv_w, nullptr, convout, OQKV, CDIM);

    dwconv_kernel<<<dim3((OQKV * NPIX) / 256), blk, 0, stream>>>(
        convout, qkv_dw_w, qkvg, OQKV);

    rnorm_kernel<<<dim3(384), blk, 0, stream>>>(qkvg, rn);

    attn_logits_kernel<<<dim3(KSPLIT, NHEADS), dim3(64), 0, stream>>>(qkvg, partial);

    attn_softmax_kernel<<<dim3(CDIM), dim3(64), 0, stream>>>(partial, rn, temp, attnm);

    attnout_kernel<<<dim3(NPIX / 256, HDDIM, NHEADS), blk, 0, stream>>>(
        qkvg, attnm, attout);

    gemm_kernel<true, true><<<dim3(128, 2), blk, 0, stream>>>(
        attout, proj_w, x_i, out_i, CDIM, CDIM);       // x1 -> d_out

    // ---- ffn branch ----
    ln_t_kernel<<<dim3(NPIX / 64), blk, 0, stream>>>(out_i, ln2_w, ln2_b, lnout);

    gemm_kernel<false, false><<<dim3(128, 8), blk, 0, stream>>>(
        lnout, ffn_in_w, nullptr, convout, OFFN, CDIM);

    dwgelu_kernel<<<dim3((HIDDEN_ * NPIX + 255) / 256), blk, 0, stream>>>(
        convout, ffn_dw_w, gated);

    gemm_kernel<true, true><<<dim3(128, 2), blk, 0, stream>>>(
        gated, ffn_out_w, out_i, out_i, CDIM, HIDDEN_); // final = x1 + conv
  }
}

// Round 7
// 1274.722 us; speedup vs baseline: 10.5287x; 1.4991x over previous
//
#include <hip/hip_runtime.h>
#include <hip/hip_bf16.h>
#include <math.h>

#define CDIM    192
#define NHEADS  4
#define HDDIM   48
#define HH      128
#define WW      128
#define NPIX    16384      // 128*128
#define OQKV    768
#define HIDDEN_ 510
#define OFFN    1020
#define LNEPS   1e-5f
#define KSPLIT  64
#define PADK    104        // 96 + 8 shorts padding (row shift 20 banks)

typedef __hip_bfloat16 bf16;
typedef __attribute__((ext_vector_type(8))) short short8;
typedef __attribute__((ext_vector_type(4))) float f32x4;

__device__ __forceinline__ float b2f(bf16 v) { return __bfloat162float(v); }
__device__ __forceinline__ bf16  f2b(float v) { return __float2bfloat16(v); }
__device__ __forceinline__ unsigned short f2bbits(float v) {
  bf16 h = __float2bfloat16(v);
  return *(unsigned short*)&h;
}

// ---------------- weight convert f32 -> bf16 ----------------
__global__ __launch_bounds__(256) void cvt_kernel(
    const float* __restrict__ src, bf16* __restrict__ dst, int n) {
  int i = blockIdx.x * 256 + threadIdx.x;
  if (i < n) dst[i] = f2b(src[i]);
}
// ffn_out [192][510] -> [192][576] zero-padded
__global__ __launch_bounds__(256) void cvt_pad_kernel(
    const float* __restrict__ src, bf16* __restrict__ dst) {
  int i = blockIdx.x * 256 + threadIdx.x;    // over 192*576
  int r = i / 576, c = i - r * 576;
  dst[i] = (c < HIDDEN_) ? f2b(src[r * HIDDEN_ + c]) : f2b(0.f);
}

// ---------------- LayerNorm over channels, per pixel. x:[C][N] f32 -> y:[N][C] bf16 ----------------
__global__ __launch_bounds__(256) void ln_t_kernel(
    const float* __restrict__ x, const float* __restrict__ w,
    const float* __restrict__ b, bf16* __restrict__ y) {
  __shared__ float red[8][64];
  __shared__ float mu_s[64], rs_s[64];
  __shared__ unsigned short tile[64 * 194];
  const int t = threadIdx.x;
  const int n0 = blockIdx.x * 64;
  const int p = t & 63, q = t >> 6;

  float s = 0.f, ss = 0.f;
  for (int c = q * 48; c < q * 48 + 48; ++c) {
    float v = x[(size_t)c * NPIX + n0 + p];
    s += v; ss += v * v;
  }
  red[q][p] = s; red[4 + q][p] = ss;
  __syncthreads();
  if (t < 64) {
    float S  = red[0][t] + red[1][t] + red[2][t] + red[3][t];
    float SS = red[4][t] + red[5][t] + red[6][t] + red[7][t];
    float mu = S * (1.f / CDIM);
    float var = SS * (1.f / CDIM) - mu * mu;
    mu_s[t] = mu; rs_s[t] = rsqrtf(var + LNEPS);
  }
  __syncthreads();
  for (int i = 0; i < 48; ++i) {
    int flat = i * 256 + t;
    int c = flat >> 6, p2 = flat & 63;
    float v = (x[(size_t)c * NPIX + n0 + p2] - mu_s[p2]) * rs_s[p2] * w[c] + b[c];
    tile[p2 * 194 + c] = f2bbits(v);
  }
  __syncthreads();
  unsigned short* yo = (unsigned short*)y + (size_t)n0 * CDIM;
  for (int i = 0; i < 48; ++i) {
    int flat = i * 256 + t;
    int pp = flat / 192, cc = flat - pp * 192;
    yo[flat] = tile[pp * 194 + cc];
  }
}

// ---------------- MFMA GEMM: out[m][n] = sum_k Wb[m][k]*act[k][n] ----------------
// Wb: bf16 [M][KA] (KA mult of 96, zero-padded cols beyond KB)
// act: BT ? [KB][NPIX] channel-major : [NPIX][KB] pixel-major (KB mult of 96 for NT)
// BM=BN=128, BK=96, 256 threads (4 waves 2x2), per-wave 64x64 (4x4 frags)
template <bool BT, bool F32OUT>
__global__ __launch_bounds__(256) void gemm_kernel(
    const bf16* __restrict__ Bact, const bf16* __restrict__ Wb,
    const float* __restrict__ res, void* __restrict__ outp,
    int M, int KA, int KB) {
  __shared__ __align__(16) unsigned short sA[128 * PADK];
  __shared__ __align__(16) unsigned short sB[128 * PADK];
  const int t = threadIdx.x;
  const int lane = t & 63;
  const int wave = t >> 6;
  const int wm = wave >> 1, wn = wave & 1;
  const int l15 = lane & 15, lk = lane >> 4;
  const int n0 = blockIdx.x * 128;
  const int m0 = blockIdx.y * 128;

  f32x4 acc[4][4];
#pragma unroll
  for (int i = 0; i < 4; ++i)
#pragma unroll
    for (int j = 0; j < 4; ++j) acc[i][j] = (f32x4){0.f, 0.f, 0.f, 0.f};

  const int Ksteps = KA / 96;
  for (int ks = 0; ks < Ksteps; ++ks) {
    const int k0 = ks * 96;
    __syncthreads();
    // ---- stage A: thread (m=t>>1, half=t&1) covers 48 k = 6 short8
    {
      const int m = t >> 1, half = t & 1;
      const int gm = m0 + m;
      short8 v[6];
      if (gm < M) {
        const short8* src = (const short8*)(Wb + (size_t)gm * KA + k0 + half * 48);
#pragma unroll
        for (int j = 0; j < 6; ++j) v[j] = src[j];
      } else {
#pragma unroll
        for (int j = 0; j < 6; ++j) v[j] = (short8){0,0,0,0,0,0,0,0};
      }
#pragma unroll
      for (int j = 0; j < 6; ++j)
        *(short8*)&sA[m * PADK + half * 48 + j * 8] = v[j];
    }
    // ---- stage B
    if (!BT) {
      // act [NPIX][KB], KB multiple of 96 (=192)
      const int n = t >> 1, half = t & 1;
      const short8* src = (const short8*)(Bact + (size_t)(n0 + n) * KB + k0 + half * 48);
      short8 v[6];
#pragma unroll
      for (int j = 0; j < 6; ++j) v[j] = src[j];
#pragma unroll
      for (int j = 0; j < 6; ++j)
        *(short8*)&sB[n * PADK + half * 48 + j * 8] = v[j];
    } else {
      // act [KB][NPIX]; transpose-stage, 3 passes of (k=t>>3 in 0..31, part=t&7)
#pragma unroll
      for (int kk = 0; kk < 3; ++kk) {
        const int k = kk * 32 + (t >> 3), part = t & 7;
        const int gk = k0 + k;
        short8 v0 = {}, v1 = {};
        if (gk < KB) {
          const short8* src = (const short8*)(Bact + (size_t)gk * NPIX + n0 + part * 16);
          v0 = src[0]; v1 = src[1];
        }
#pragma unroll
        for (int j = 0; j < 8; ++j) {
          sB[(part * 16 + j) * PADK + k]     = (unsigned short)v0[j];
          sB[(part * 16 + 8 + j) * PADK + k] = (unsigned short)v1[j];
        }
      }
    }
    __syncthreads();
    // ---- 3 sub-k MFMA passes
#pragma unroll
    for (int sk = 0; sk < 3; ++sk) {
      short8 af[4], bf_[4];
#pragma unroll
      for (int mf = 0; mf < 4; ++mf)
        af[mf] = *(const short8*)&sA[(wm * 64 + mf * 16 + l15) * PADK + sk * 32 + lk * 8];
#pragma unroll
      for (int nf = 0; nf < 4; ++nf)
        bf_[nf] = *(const short8*)&sB[(wn * 64 + nf * 16 + l15) * PADK + sk * 32 + lk * 8];
#pragma unroll
      for (int mf = 0; mf < 4; ++mf)
#pragma unroll
        for (int nf = 0; nf < 4; ++nf)
          acc[mf][nf] = __builtin_amdgcn_mfma_f32_16x16x32_bf16(
              af[mf], bf_[nf], acc[mf][nf], 0, 0, 0);
    }
  }

  // ---- epilogue: D col = lane&15 (n), row = (lane>>4)*4 + reg (m)
#pragma unroll
  for (int mf = 0; mf < 4; ++mf) {
#pragma unroll
    for (int nf = 0; nf < 4; ++nf) {
#pragma unroll
      for (int r = 0; r < 4; ++r) {
        int m = m0 + wm * 64 + mf * 16 + lk * 4 + r;
        int n = n0 + wn * 64 + nf * 16 + l15;
        if (m < M) {
          size_t off = (size_t)m * NPIX + n;
          if (F32OUT) ((float*)outp)[off] = acc[mf][nf][r] + res[off];
          else        ((bf16*)outp)[off]  = f2b(acc[mf][nf][r]);
        }
      }
    }
  }
}

// ---------------- depthwise 3x3, zero pad 1, [C][N] bf16 -> [C][N] bf16 ----------------
__global__ __launch_bounds__(256) void dwconv_kernel(
    const bf16* __restrict__ in, const float* __restrict__ w,
    bf16* __restrict__ out, int Ch) {
  size_t idx = (size_t)blockIdx.x * blockDim.x + threadIdx.x;
  if (idx >= (size_t)Ch * NPIX) return;
  int n = (int)(idx % NPIX);
  int ch = (int)(idx / NPIX);
  int y = n / WW, x = n % WW;
  const bf16* ip = in + (size_t)ch * NPIX;
  const float* wp = w + (size_t)ch * 9;
  float acc = 0.f;
#pragma unroll
  for (int ky = 0; ky < 3; ++ky) {
    int yy = y + ky - 1;
    if (yy < 0 || yy >= HH) continue;
#pragma unroll
    for (int kx = 0; kx < 3; ++kx) {
      int xx = x + kx - 1;
      if (xx < 0 || xx >= WW) continue;
      acc += wp[ky * 3 + kx] * b2f(ip[yy * WW + xx]);
    }
  }
  out[idx] = f2b(acc);
}

// ---------------- fused FFN dwconv3x3 + gelu(x1)*x2 ----------------
__global__ __launch_bounds__(256) void dwgelu_kernel(
    const bf16* __restrict__ in, const float* __restrict__ w,
    bf16* __restrict__ out) {
  size_t idx = (size_t)blockIdx.x * blockDim.x + threadIdx.x;
  if (idx >= (size_t)HIDDEN_ * NPIX) return;
  int n = (int)(idx % NPIX);
  int ch = (int)(idx / NPIX);
  int y = n / WW, x = n % WW;
  const bf16* ip1 = in + (size_t)ch * NPIX;
  const bf16* ip2 = ip1 + (size_t)HIDDEN_ * NPIX;
  const float* wp1 = w + (size_t)ch * 9;
  const float* wp2 = w + (size_t)(ch + HIDDEN_) * 9;
  float a1 = 0.f, a2 = 0.f;
#pragma unroll
  for (int ky = 0; ky < 3; ++ky) {
    int yy = y + ky - 1;
    if (yy < 0 || yy >= HH) continue;
#pragma unroll
    for (int kx = 0; kx < 3; ++kx) {
      int xx = x + kx - 1;
      if (xx < 0 || xx >= WW) continue;
      int o = yy * WW + xx;
      a1 += wp1[ky * 3 + kx] * b2f(ip1[o]);
      a2 += wp2[ky * 3 + kx] * b2f(ip2[o]);
    }
  }
  float ge = 0.5f * a1 * (1.f + erff(a1 * 0.70710678118f));
  out[idx] = f2b(ge * a2);
}

// ---------------- per-channel 1/max(||row||,1e-12) for q and k ----------------
__global__ __launch_bounds__(256) void rnorm_kernel(
    const bf16* __restrict__ qkvg, float* __restrict__ rn) {
  int ci = blockIdx.x;
  int ch = (ci < 192) ? ci : (ci + 192);
  const bf16* p = qkvg + (size_t)ch * NPIX;
  float s = 0.f;
  for (int i = threadIdx.x; i < NPIX; i += blockDim.x) {
    float v = b2f(p[i]); s += v * v;
  }
  for (int off = 32; off; off >>= 1) s += __shfl_down(s, off);
  __shared__ float red[4];
  int wave = threadIdx.x >> 6, lane = threadIdx.x & 63;
  if (lane == 0) red[wave] = s;
  __syncthreads();
  if (threadIdx.x == 0) {
    float tsum = red[0] + red[1] + red[2] + red[3];
    rn[ci] = 1.f / fmaxf(sqrtf(tsum), 1e-12f);
  }
}

// ---------------- attention logits via split-K MFMA ----------------
__global__ __launch_bounds__(64) void attn_logits_kernel(
    const bf16* __restrict__ qkvg, float* __restrict__ part) {
  const int ks = blockIdx.x, h = blockIdx.y;
  const int lane = threadIdx.x;
  const int l15 = lane & 15, lk = lane >> 4;
  const bf16* qbase = qkvg + (size_t)(h * HDDIM) * NPIX;
  const bf16* kbase = qkvg + (size_t)(384 + h * HDDIM) * NPIX;

  f32x4 acc[3][3];
#pragma unroll
  for (int i = 0; i < 3; ++i)
#pragma unroll
    for (int j = 0; j < 3; ++j) acc[i][j] = (f32x4){0.f, 0.f, 0.f, 0.f};

  const int n_start = ks * (NPIX / KSPLIT);
  for (int n0 = n_start; n0 < n_start + NPIX / KSPLIT; n0 += 32) {
    short8 af[3], bfr[3];
#pragma unroll
    for (int i = 0; i < 3; ++i)
      af[i] = *(const short8*)(qbase + (size_t)(i * 16 + l15) * NPIX + n0 + lk * 8);
#pragma unroll
    for (int j = 0; j < 3; ++j)
      bfr[j] = *(const short8*)(kbase + (size_t)(j * 16 + l15) * NPIX + n0 + lk * 8);
#pragma unroll
    for (int i = 0; i < 3; ++i)
#pragma unroll
      for (int j = 0; j < 3; ++j)
        acc[i][j] = __builtin_amdgcn_mfma_f32_16x16x32_bf16(af[i], bfr[j], acc[i][j], 0, 0, 0);
  }

  float* pp = part + ((size_t)(ks * NHEADS + h)) * (HDDIM * HDDIM);
#pragma unroll
  for (int i = 0; i < 3; ++i)
#pragma unroll
    for (int j = 0; j < 3; ++j)
#pragma unroll
      for (int r = 0; r < 4; ++r) {
        int row = i * 16 + lk * 4 + r;
        int col = j * 16 + l15;
        pp[row * HDDIM + col] = acc[i][j][r];
      }
}

// ---------------- reduce partials + scale + softmax ----------------
__global__ __launch_bounds__(64) void attn_softmax_kernel(
    const float* __restrict__ part, const float* __restrict__ rn,
    const float* __restrict__ temp, float* __restrict__ attn) {
  int g = blockIdx.x;
  int h = g / HDDIM, c = g % HDDIM;
  int d = threadIdx.x;
  float v = 0.f;
  if (d < HDDIM) {
    for (int ks = 0; ks < KSPLIT; ++ks)
      v += part[((size_t)(ks * NHEADS + h)) * (HDDIM * HDDIM) + c * HDDIM + d];
    v *= rn[g] * rn[192 + h * HDDIM + d] * temp[h];
  }
  float lv = (d < HDDIM) ? v : -1e30f;
  float m = lv;
  for (int off = 32; off; off >>= 1) m = fmaxf(m, __shfl_xor(m, off));
  float e = (d < HDDIM) ? expf(lv - m) : 0.f;
  float s = e;
  for (int off = 32; off; off >>= 1) s += __shfl_xor(s, off);
  if (d < HDDIM) attn[(size_t)g * HDDIM + d] = e / s;
}

// ---------------- out = (attn @ v) * sigmoid(gate) -> [C][N] bf16 ----------------
__global__ __launch_bounds__(256) void attnout_kernel(
    const bf16* __restrict__ qkvg, const float* __restrict__ attn,
    bf16* __restrict__ out) {
  int n = blockIdx.x * blockDim.x + threadIdx.x;
  int c = blockIdx.y;
  int h = blockIdx.z;
  int g = h * HDDIM + c;
  __shared__ float a[HDDIM];
  if (threadIdx.x < HDDIM)
    a[threadIdx.x] = attn[(size_t)(h * HDDIM + c) * HDDIM + threadIdx.x];
  __syncthreads();
  const bf16* vbase = qkvg + (size_t)(576 + h * HDDIM) * NPIX + n;
  float acc = 0.f;
#pragma unroll 8
  for (int d = 0; d < HDDIM; ++d) acc += a[d] * b2f(vbase[(size_t)d * NPIX]);
  float gate = b2f(qkvg[(size_t)(192 + g) * NPIX + n]);
  float sg = 1.f / (1.f + expf(-gate));
  out[(size_t)g * NPIX + n] = f2b(acc * sg);
}

extern "C" void kernel_launch(void* const* d_in, const int* in_sizes, int n_in,
                              void* d_out, int out_size, void* d_ws, size_t ws_size,
                              hipStream_t stream) {
  const float* x        = (const float*)d_in[0];
  const float* ln1_w    = (const float*)d_in[1];
  const float* ln1_b    = (const float*)d_in[2];
  const float* qkv_w    = (const float*)d_in[3];
  const float* qkv_dw_w = (const float*)d_in[4];
  const float* temp     = (const float*)d_in[5];
  const float* proj_w   = (const float*)d_in[6];
  const float* ln2_w    = (const float*)d_in[7];
  const float* ln2_b    = (const float*)d_in[8];
  const float* ffn_in_w = (const float*)d_in[9];
  const float* ffn_dw_w = (const float*)d_in[10];
  const float* ffn_out_w= (const float*)d_in[11];
  float* out = (float*)d_out;

  // per-image workspace (~88 MiB total)
  char* p = (char*)d_ws;
  bf16*  lnout   = (bf16*)p;  p += (size_t)NPIX * CDIM    * sizeof(bf16);  //  6 MiB
  bf16*  convout = (bf16*)p;  p += (size_t)NPIX * OFFN    * sizeof(bf16);  // 32 MiB
  bf16*  qkvg    = (bf16*)p;  p += (size_t)NPIX * OQKV    * sizeof(bf16);  // 24 MiB
  bf16*  gated   = (bf16*)p;  p += (size_t)NPIX * HIDDEN_ * sizeof(bf16);  // 16 MiB
  bf16*  attout  = (bf16*)p;  p += (size_t)NPIX * CDIM    * sizeof(bf16);  //  6 MiB
  float* rn      = (float*)p; p += 384 * sizeof(float);
  float* attnm   = (float*)p; p += NHEADS * HDDIM * HDDIM * sizeof(float);
  float* partial = (float*)p; p += (size_t)KSPLIT * NHEADS * HDDIM * HDDIM * sizeof(float);
  bf16*  wq      = (bf16*)p;  p += (size_t)OQKV * CDIM * sizeof(bf16);     // 768x192
  bf16*  wp_     = (bf16*)p;  p += (size_t)CDIM * CDIM * sizeof(bf16);     // 192x192
  bf16*  wfi     = (bf16*)p;  p += (size_t)OFFN * CDIM * sizeof(bf16);     // 1020x192
  bf16*  wfo     = (bf16*)p;  p += (size_t)CDIM * 576  * sizeof(bf16);     // 192x576 padded

  dim3 blk(256);

  // ---- weights -> bf16 (once per launch) ----
  cvt_kernel<<<dim3((OQKV * CDIM) / 256), blk, 0, stream>>>(qkv_w, wq, OQKV * CDIM);
  cvt_kernel<<<dim3((CDIM * CDIM) / 256), blk, 0, stream>>>(proj_w, wp_, CDIM * CDIM);
  cvt_kernel<<<dim3((OFFN * CDIM) / 256), blk, 0, stream>>>(ffn_in_w, wfi, OFFN * CDIM);
  cvt_pad_kernel<<<dim3((CDIM * 576) / 256), blk, 0, stream>>>(ffn_out_w, wfo);

  for (int img = 0; img < 4; ++img) {
    const float* x_i = x + (size_t)img * CDIM * NPIX;
    float* out_i = out + (size_t)img * CDIM * NPIX;

    // ---- attention branch ----
    ln_t_kernel<<<dim3(NPIX / 64), blk, 0, stream>>>(x_i, ln1_w, ln1_b, lnout);

    gemm_kernel<false, false><<<dim3(128, OQKV / 128), blk, 0, stream>>>(
        lnout, wq, nullptr, convout, OQKV, CDIM, CDIM);

    dwconv_kernel<<<dim3((OQKV * NPIX) / 256), blk, 0, stream>>>(
        convout, qkv_dw_w, qkvg, OQKV);

    rnorm_kernel<<<dim3(384), blk, 0, stream>>>(qkvg, rn);

    attn_logits_kernel<<<dim3(KSPLIT, NHEADS), dim3(64), 0, stream>>>(qkvg, partial);

    attn_softmax_kernel<<<dim3(CDIM), dim3(64), 0, stream>>>(partial, rn, temp, attnm);

    attnout_kernel<<<dim3(NPIX / 256, HDDIM, NHEADS), blk, 0, stream>>>(
        qkvg, attnm, attout);

    gemm_kernel<true, true><<<dim3(128, 2), blk, 0, stream>>>(
        attout, wp_, x_i, out_i, CDIM, CDIM, CDIM);     // x1 -> d_out

    // ---- ffn branch ----
    ln_t_kernel<<<dim3(NPIX / 64), blk, 0, stream>>>(out_i, ln2_w, ln2_b, lnout);

    gemm_kernel<false, false><<<dim3(128, 8), blk, 0, stream>>>(
        lnout, wfi, nullptr, convout, OFFN, CDIM, CDIM);

    dwgelu_kernel<<<dim3((HIDDEN_ * NPIX + 255) / 256), blk, 0, stream>>>(
        convout, ffn_dw_w, gated);

    gemm_kernel<true, true><<<dim3(128, 2), blk, 0, stream>>>(
        gated, wfo, out_i, out_i, CDIM, 576, HIDDEN_);  // final = x1 + conv
  }
}

// Round 9
// 936.827 us; speedup vs baseline: 14.3262x; 1.3607x over previous
//
#include <hip/hip_runtime.h>
#include <hip/hip_bf16.h>
#include <math.h>

#define CDIM    192
#define NHEADS  4
#define HDDIM   48
#define HH      128
#define WW      128
#define NPIX    16384      // 128*128
#define OQKV    768
#define HIDDEN_ 510
#define OFFN    1020
#define LNEPS   1e-5f
#define KSPLIT  64
#define PADK    104        // 96 + 8 shorts padding

typedef __hip_bfloat16 bf16;
typedef __attribute__((ext_vector_type(8))) short short8;
typedef __attribute__((ext_vector_type(4))) float f32x4;

__device__ __forceinline__ float b2f(bf16 v) { return __bfloat162float(v); }
__device__ __forceinline__ bf16  f2b(float v) { return __float2bfloat16(v); }
__device__ __forceinline__ unsigned short f2bbits(float v) {
  bf16 h = __float2bfloat16(v);
  return *(unsigned short*)&h;
}
__device__ __forceinline__ float us2f(unsigned short u) {
  union { unsigned int i; float f; } cv; cv.i = ((unsigned int)u) << 16; return cv.f;
}

// ---------------- weight convert f32 -> bf16 ----------------
__global__ __launch_bounds__(256) void cvt_kernel(
    const float* __restrict__ src, bf16* __restrict__ dst, int n) {
  int i = blockIdx.x * 256 + threadIdx.x;
  if (i < n) dst[i] = f2b(src[i]);
}
// ffn_out [192][510] -> [192][576] zero-padded
__global__ __launch_bounds__(256) void cvt_pad_kernel(
    const float* __restrict__ src, bf16* __restrict__ dst) {
  int i = blockIdx.x * 256 + threadIdx.x;    // over 192*576
  int r = i / 576, c = i - r * 576;
  dst[i] = (c < HIDDEN_) ? f2b(src[r * HIDDEN_ + c]) : f2b(0.f);
}

// ---------------- LayerNorm over channels, per pixel. x:[C][N] f32 -> y:[N][C] bf16 ----------------
__global__ __launch_bounds__(256) void ln_t_kernel(
    const float* __restrict__ x, const float* __restrict__ w,
    const float* __restrict__ b, bf16* __restrict__ y) {
  __shared__ float red[8][64];
  __shared__ float mu_s[64], rs_s[64];
  __shared__ unsigned short tile[64 * 194];
  const int t = threadIdx.x;
  const int n0 = blockIdx.x * 64;
  const int p = t & 63, q = t >> 6;

  float s = 0.f, ss = 0.f;
  for (int c = q * 48; c < q * 48 + 48; ++c) {
    float v = x[(size_t)c * NPIX + n0 + p];
    s += v; ss += v * v;
  }
  red[q][p] = s; red[4 + q][p] = ss;
  __syncthreads();
  if (t < 64) {
    float S  = red[0][t] + red[1][t] + red[2][t] + red[3][t];
    float SS = red[4][t] + red[5][t] + red[6][t] + red[7][t];
    float mu = S * (1.f / CDIM);
    float var = SS * (1.f / CDIM) - mu * mu;
    mu_s[t] = mu; rs_s[t] = rsqrtf(var + LNEPS);
  }
  __syncthreads();
  for (int i = 0; i < 48; ++i) {
    int flat = i * 256 + t;
    int c = flat >> 6, p2 = flat & 63;
    float v = (x[(size_t)c * NPIX + n0 + p2] - mu_s[p2]) * rs_s[p2] * w[c] + b[c];
    tile[p2 * 194 + c] = f2bbits(v);
  }
  __syncthreads();
  unsigned short* yo = (unsigned short*)y + (size_t)n0 * CDIM;
  for (int i = 0; i < 48; ++i) {
    int flat = i * 256 + t;
    int pp = flat / 192, cc = flat - pp * 192;
    yo[flat] = tile[pp * 194 + cc];
  }
}

// ---------------- MFMA GEMM: out[m][n] = sum_k Wb[m][k]*act[k][n] ----------------
template <bool BT, bool F32OUT>
__global__ __launch_bounds__(256) void gemm_kernel(
    const bf16* __restrict__ Bact, const bf16* __restrict__ Wb,
    const float* __restrict__ res, void* __restrict__ outp,
    int M, int KA, int KB) {
  __shared__ __align__(16) unsigned short sA[128 * PADK];
  __shared__ __align__(16) unsigned short sB[128 * PADK];
  const int t = threadIdx.x;
  const int lane = t & 63;
  const int wave = t >> 6;
  const int wm = wave >> 1, wn = wave & 1;
  const int l15 = lane & 15, lk = lane >> 4;
  const int n0 = blockIdx.x * 128;
  const int m0 = blockIdx.y * 128;

  f32x4 acc[4][4];
#pragma unroll
  for (int i = 0; i < 4; ++i)
#pragma unroll
    for (int j = 0; j < 4; ++j) acc[i][j] = (f32x4){0.f, 0.f, 0.f, 0.f};

  const int Ksteps = KA / 96;
  for (int ks = 0; ks < Ksteps; ++ks) {
    const int k0 = ks * 96;
    __syncthreads();
    {
      const int m = t >> 1, half = t & 1;
      const int gm = m0 + m;
      short8 v[6];
      if (gm < M) {
        const short8* src = (const short8*)(Wb + (size_t)gm * KA + k0 + half * 48);
#pragma unroll
        for (int j = 0; j < 6; ++j) v[j] = src[j];
      } else {
#pragma unroll
        for (int j = 0; j < 6; ++j) v[j] = (short8){0,0,0,0,0,0,0,0};
      }
#pragma unroll
      for (int j = 0; j < 6; ++j)
        *(short8*)&sA[m * PADK + half * 48 + j * 8] = v[j];
    }
    if (!BT) {
      const int n = t >> 1, half = t & 1;
      const short8* src = (const short8*)(Bact + (size_t)(n0 + n) * KB + k0 + half * 48);
      short8 v[6];
#pragma unroll
      for (int j = 0; j < 6; ++j) v[j] = src[j];
#pragma unroll
      for (int j = 0; j < 6; ++j)
        *(short8*)&sB[n * PADK + half * 48 + j * 8] = v[j];
    } else {
#pragma unroll
      for (int kk = 0; kk < 3; ++kk) {
        const int k = kk * 32 + (t >> 3), part = t & 7;
        const int gk = k0 + k;
        short8 v0 = {}, v1 = {};
        if (gk < KB) {
          const short8* src = (const short8*)(Bact + (size_t)gk * NPIX + n0 + part * 16);
          v0 = src[0]; v1 = src[1];
        }
#pragma unroll
        for (int j = 0; j < 8; ++j) {
          sB[(part * 16 + j) * PADK + k]     = (unsigned short)v0[j];
          sB[(part * 16 + 8 + j) * PADK + k] = (unsigned short)v1[j];
        }
      }
    }
    __syncthreads();
#pragma unroll
    for (int sk = 0; sk < 3; ++sk) {
      short8 af[4], bf_[4];
#pragma unroll
      for (int mf = 0; mf < 4; ++mf)
        af[mf] = *(const short8*)&sA[(wm * 64 + mf * 16 + l15) * PADK + sk * 32 + lk * 8];
#pragma unroll
      for (int nf = 0; nf < 4; ++nf)
        bf_[nf] = *(const short8*)&sB[(wn * 64 + nf * 16 + l15) * PADK + sk * 32 + lk * 8];
#pragma unroll
      for (int mf = 0; mf < 4; ++mf)
#pragma unroll
        for (int nf = 0; nf < 4; ++nf)
          acc[mf][nf] = __builtin_amdgcn_mfma_f32_16x16x32_bf16(
              af[mf], bf_[nf], acc[mf][nf], 0, 0, 0);
    }
  }

#pragma unroll
  for (int mf = 0; mf < 4; ++mf) {
#pragma unroll
    for (int nf = 0; nf < 4; ++nf) {
#pragma unroll
      for (int r = 0; r < 4; ++r) {
        int m = m0 + wm * 64 + mf * 16 + lk * 4 + r;
        int n = n0 + wn * 64 + nf * 16 + l15;
        if (m < M) {
          size_t off = (size_t)m * NPIX + n;
          if (F32OUT) ((float*)outp)[off] = acc[mf][nf][r] + res[off];
          else        ((bf16*)outp)[off]  = f2b(acc[mf][nf][r]);
        }
      }
    }
  }
}

// ---------------- vectorized depthwise 3x3: 8 px / thread ----------------
// grid: Ch * 2048 / 256 blocks
__global__ __launch_bounds__(256) void dwconv_v_kernel(
    const bf16* __restrict__ in, const float* __restrict__ w,
    bf16* __restrict__ out, int Ch) {
  const int idx = blockIdx.x * 256 + threadIdx.x;
  const int ch = idx >> 11;              // / 2048
  const int rem = idx & 2047;
  const int y = rem >> 4;                // 16 x-blocks per row
  const int x8 = (rem & 15) * 8;
  const unsigned short* ip = (const unsigned short*)in + (size_t)ch * NPIX;
  const float* wp = w + ch * 9;

  float acc[8];
#pragma unroll
  for (int i = 0; i < 8; ++i) acc[i] = 0.f;

#pragma unroll
  for (int ky = 0; ky < 3; ++ky) {
    int yy = y + ky - 1;
    if (yy < 0 || yy >= HH) continue;
    const unsigned short* rp = ip + yy * WW + x8;
    float vals[10];
    short8 mv = *(const short8*)rp;
    vals[0] = (x8 > 0) ? us2f(rp[-1]) : 0.f;
#pragma unroll
    for (int j = 0; j < 8; ++j) vals[1 + j] = us2f((unsigned short)mv[j]);
    vals[9] = (x8 + 8 < WW) ? us2f(rp[8]) : 0.f;
    float w0 = wp[ky * 3], w1 = wp[ky * 3 + 1], w2 = wp[ky * 3 + 2];
#pragma unroll
    for (int xx = 0; xx < 8; ++xx)
      acc[xx] += w0 * vals[xx] + w1 * vals[xx + 1] + w2 * vals[xx + 2];
  }

  short8 o;
#pragma unroll
  for (int xx = 0; xx < 8; ++xx) o[xx] = (short)f2bbits(acc[xx]);
  *(short8*)((unsigned short*)out + (size_t)ch * NPIX + y * WW + x8) = o;
}

// ---------------- vectorized fused FFN dwconv3x3 + gelu(x1)*x2 : 8 px / thread ----------------
// grid: 510 * 2048 / 256 blocks (idx over ch*2048)
__global__ __launch_bounds__(256) void dwgelu_v_kernel(
    const bf16* __restrict__ in, const float* __restrict__ w,
    bf16* __restrict__ out) {
  const int idx = blockIdx.x * 256 + threadIdx.x;
  const int ch = idx >> 11;
  if (ch >= HIDDEN_) return;
  const int rem = idx & 2047;
  const int y = rem >> 4;
  const int x8 = (rem & 15) * 8;
  const unsigned short* ip1 = (const unsigned short*)in + (size_t)ch * NPIX;
  const unsigned short* ip2 = ip1 + (size_t)HIDDEN_ * NPIX;
  const float* wp1 = w + ch * 9;
  const float* wp2 = w + (ch + HIDDEN_) * 9;

  float a1[8], a2[8];
#pragma unroll
  for (int i = 0; i < 8; ++i) { a1[i] = 0.f; a2[i] = 0.f; }

#pragma unroll
  for (int ky = 0; ky < 3; ++ky) {
    int yy = y + ky - 1;
    if (yy < 0 || yy >= HH) continue;
    {
      const unsigned short* rp = ip1 + yy * WW + x8;
      float vals[10];
      short8 mv = *(const short8*)rp;
      vals[0] = (x8 > 0) ? us2f(rp[-1]) : 0.f;
#pragma unroll
      for (int j = 0; j < 8; ++j) vals[1 + j] = us2f((unsigned short)mv[j]);
      vals[9] = (x8 + 8 < WW) ? us2f(rp[8]) : 0.f;
      float w0 = wp1[ky * 3], w1 = wp1[ky * 3 + 1], w2 = wp1[ky * 3 + 2];
#pragma unroll
      for (int xx = 0; xx < 8; ++xx)
        a1[xx] += w0 * vals[xx] + w1 * vals[xx + 1] + w2 * vals[xx + 2];
    }
    {
      const unsigned short* rp = ip2 + yy * WW + x8;
      float vals[10];
      short8 mv = *(const short8*)rp;
      vals[0] = (x8 > 0) ? us2f(rp[-1]) : 0.f;
#pragma unroll
      for (int j = 0; j < 8; ++j) vals[1 + j] = us2f((unsigned short)mv[j]);
      vals[9] = (x8 + 8 < WW) ? us2f(rp[8]) : 0.f;
      float w0 = wp2[ky * 3], w1 = wp2[ky * 3 + 1], w2 = wp2[ky * 3 + 2];
#pragma unroll
      for (int xx = 0; xx < 8; ++xx)
        a2[xx] += w0 * vals[xx] + w1 * vals[xx + 1] + w2 * vals[xx + 2];
    }
  }

  short8 o;
#pragma unroll
  for (int xx = 0; xx < 8; ++xx) {
    float ge = 0.5f * a1[xx] * (1.f + erff(a1[xx] * 0.70710678118f));
    o[xx] = (short)f2bbits(ge * a2[xx]);
  }
  *(short8*)((unsigned short*)out + (size_t)ch * NPIX + y * WW + x8) = o;
}

// ---------------- per-channel 1/max(||row||,1e-12) for q and k ----------------
__global__ __launch_bounds__(256) void rnorm_kernel(
    const bf16* __restrict__ qkvg, float* __restrict__ rn) {
  int ci = blockIdx.x;
  int ch = (ci < 192) ? ci : (ci + 192);
  const bf16* p = qkvg + (size_t)ch * NPIX;
  float s = 0.f;
  for (int i = threadIdx.x; i < NPIX; i += blockDim.x) {
    float v = b2f(p[i]); s += v * v;
  }
  for (int off = 32; off; off >>= 1) s += __shfl_down(s, off);
  __shared__ float red[4];
  int wave = threadIdx.x >> 6, lane = threadIdx.x & 63;
  if (lane == 0) red[wave] = s;
  __syncthreads();
  if (threadIdx.x == 0) {
    float tsum = red[0] + red[1] + red[2] + red[3];
    rn[ci] = 1.f / fmaxf(sqrtf(tsum), 1e-12f);
  }
}

// ---------------- attention logits via split-K MFMA ----------------
__global__ __launch_bounds__(64) void attn_logits_kernel(
    const bf16* __restrict__ qkvg, float* __restrict__ part) {
  const int ks = blockIdx.x, h = blockIdx.y;
  const int lane = threadIdx.x;
  const int l15 = lane & 15, lk = lane >> 4;
  const bf16* qbase = qkvg + (size_t)(h * HDDIM) * NPIX;
  const bf16* kbase = qkvg + (size_t)(384 + h * HDDIM) * NPIX;

  f32x4 acc[3][3];
#pragma unroll
  for (int i = 0; i < 3; ++i)
#pragma unroll
    for (int j = 0; j < 3; ++j) acc[i][j] = (f32x4){0.f, 0.f, 0.f, 0.f};

  const int n_start = ks * (NPIX / KSPLIT);
  for (int n0 = n_start; n0 < n_start + NPIX / KSPLIT; n0 += 32) {
    short8 af[3], bfr[3];
#pragma unroll
    for (int i = 0; i < 3; ++i)
      af[i] = *(const short8*)(qbase + (size_t)(i * 16 + l15) * NPIX + n0 + lk * 8);
#pragma unroll
    for (int j = 0; j < 3; ++j)
      bfr[j] = *(const short8*)(kbase + (size_t)(j * 16 + l15) * NPIX + n0 + lk * 8);
#pragma unroll
    for (int i = 0; i < 3; ++i)
#pragma unroll
      for (int j = 0; j < 3; ++j)
        acc[i][j] = __builtin_amdgcn_mfma_f32_16x16x32_bf16(af[i], bfr[j], acc[i][j], 0, 0, 0);
  }

  float* pp = part + ((size_t)(ks * NHEADS + h)) * (HDDIM * HDDIM);
#pragma unroll
  for (int i = 0; i < 3; ++i)
#pragma unroll
    for (int j = 0; j < 3; ++j)
#pragma unroll
      for (int r = 0; r < 4; ++r) {
        int row = i * 16 + lk * 4 + r;
        int col = j * 16 + l15;
        pp[row * HDDIM + col] = acc[i][j][r];
      }
}

// ---------------- reduce partials + scale + softmax ----------------
__global__ __launch_bounds__(64) void attn_softmax_kernel(
    const float* __restrict__ part, const float* __restrict__ rn,
    const float* __restrict__ temp, float* __restrict__ attn) {
  int g = blockIdx.x;
  int h = g / HDDIM, c = g % HDDIM;
  int d = threadIdx.x;
  float v = 0.f;
  if (d < HDDIM) {
    for (int ks = 0; ks < KSPLIT; ++ks)
      v += part[((size_t)(ks * NHEADS + h)) * (HDDIM * HDDIM) + c * HDDIM + d];
    v *= rn[g] * rn[192 + h * HDDIM + d] * temp[h];
  }
  float lv = (d < HDDIM) ? v : -1e30f;
  float m = lv;
  for (int off = 32; off; off >>= 1) m = fmaxf(m, __shfl_xor(m, off));
  float e = (d < HDDIM) ? expf(lv - m) : 0.f;
  float s = e;
  for (int off = 32; off; off >>= 1) s += __shfl_xor(s, off);
  if (d < HDDIM) attn[(size_t)g * HDDIM + d] = e / s;
}

// ---------------- out = (attn @ v) * sigmoid(gate) -> [C][N] bf16 ----------------
__global__ __launch_bounds__(256) void attnout_kernel(
    const bf16* __restrict__ qkvg, const float* __restrict__ attn,
    bf16* __restrict__ out) {
  int n = blockIdx.x * blockDim.x + threadIdx.x;
  int c = blockIdx.y;
  int h = blockIdx.z;
  int g = h * HDDIM + c;
  __shared__ float a[HDDIM];
  if (threadIdx.x < HDDIM)
    a[threadIdx.x] = attn[(size_t)(h * HDDIM + c) * HDDIM + threadIdx.x];
  __syncthreads();
  const bf16* vbase = qkvg + (size_t)(576 + h * HDDIM) * NPIX + n;
  float acc = 0.f;
#pragma unroll 8
  for (int d = 0; d < HDDIM; ++d) acc += a[d] * b2f(vbase[(size_t)d * NPIX]);
  float gate = b2f(qkvg[(size_t)(192 + g) * NPIX + n]);
  float sg = 1.f / (1.f + expf(-gate));
  out[(size_t)g * NPIX + n] = f2b(acc * sg);
}

extern "C" void kernel_launch(void* const* d_in, const int* in_sizes, int n_in,
                              void* d_out, int out_size, void* d_ws, size_t ws_size,
                              hipStream_t stream) {
  const float* x        = (const float*)d_in[0];
  const float* ln1_w    = (const float*)d_in[1];
  const float* ln1_b    = (const float*)d_in[2];
  const float* qkv_w    = (const float*)d_in[3];
  const float* qkv_dw_w = (const float*)d_in[4];
  const float* temp     = (const float*)d_in[5];
  const float* proj_w   = (const float*)d_in[6];
  const float* ln2_w    = (const float*)d_in[7];
  const float* ln2_b    = (const float*)d_in[8];
  const float* ffn_in_w = (const float*)d_in[9];
  const float* ffn_dw_w = (const float*)d_in[10];
  const float* ffn_out_w= (const float*)d_in[11];
  float* out = (float*)d_out;

  // per-image workspace (~88 MiB total)
  char* p = (char*)d_ws;
  bf16*  lnout   = (bf16*)p;  p += (size_t)NPIX * CDIM    * sizeof(bf16);
  bf16*  convout = (bf16*)p;  p += (size_t)NPIX * OFFN    * sizeof(bf16);
  bf16*  qkvg    = (bf16*)p;  p += (size_t)NPIX * OQKV    * sizeof(bf16);
  bf16*  gated   = (bf16*)p;  p += (size_t)NPIX * HIDDEN_ * sizeof(bf16);
  bf16*  attout  = (bf16*)p;  p += (size_t)NPIX * CDIM    * sizeof(bf16);
  float* rn      = (float*)p; p += 384 * sizeof(float);
  float* attnm   = (float*)p; p += NHEADS * HDDIM * HDDIM * sizeof(float);
  float* partial = (float*)p; p += (size_t)KSPLIT * NHEADS * HDDIM * HDDIM * sizeof(float);
  bf16*  wq      = (bf16*)p;  p += (size_t)OQKV * CDIM * sizeof(bf16);
  bf16*  wp_     = (bf16*)p;  p += (size_t)CDIM * CDIM * sizeof(bf16);
  bf16*  wfi     = (bf16*)p;  p += (size_t)OFFN * CDIM * sizeof(bf16);
  bf16*  wfo     = (bf16*)p;  p += (size_t)CDIM * 576  * sizeof(bf16);

  dim3 blk(256);

  // ---- weights -> bf16 (once per launch) ----
  cvt_kernel<<<dim3((OQKV * CDIM) / 256), blk, 0, stream>>>(qkv_w, wq, OQKV * CDIM);
  cvt_kernel<<<dim3((CDIM * CDIM) / 256), blk, 0, stream>>>(proj_w, wp_, CDIM * CDIM);
  cvt_kernel<<<dim3((OFFN * CDIM) / 256), blk, 0, stream>>>(ffn_in_w, wfi, OFFN * CDIM);
  cvt_pad_kernel<<<dim3((CDIM * 576) / 256), blk, 0, stream>>>(ffn_out_w, wfo);

  for (int img = 0; img < 4; ++img) {
    const float* x_i = x + (size_t)img * CDIM * NPIX;
    float* out_i = out + (size_t)img * CDIM * NPIX;

    // ---- attention branch ----
    ln_t_kernel<<<dim3(NPIX / 64), blk, 0, stream>>>(x_i, ln1_w, ln1_b, lnout);

    gemm_kernel<false, false><<<dim3(128, OQKV / 128), blk, 0, stream>>>(
        lnout, wq, nullptr, convout, OQKV, CDIM, CDIM);

    dwconv_v_kernel<<<dim3((OQKV * 2048) / 256), blk, 0, stream>>>(
        convout, qkv_dw_w, qkvg, OQKV);

    rnorm_kernel<<<dim3(384), blk, 0, stream>>>(qkvg, rn);

    attn_logits_kernel<<<dim3(KSPLIT, NHEADS), dim3(64), 0, stream>>>(qkvg, partial);

    attn_softmax_kernel<<<dim3(CDIM), dim3(64), 0, stream>>>(partial, rn, temp, attnm);

    attnout_kernel<<<dim3(NPIX / 256, HDDIM, NHEADS), blk, 0, stream>>>(
        qkvg, attnm, attout);

    gemm_kernel<true, true><<<dim3(128, 2), blk, 0, stream>>>(
        attout, wp_, x_i, out_i, CDIM, CDIM, CDIM);     // x1 -> d_out

    // ---- ffn branch ----
    ln_t_kernel<<<dim3(NPIX / 64), blk, 0, stream>>>(out_i, ln2_w, ln2_b, lnout);

    gemm_kernel<false, false><<<dim3(128, 8), blk, 0, stream>>>(
        lnout, wfi, nullptr, convout, OFFN, CDIM, CDIM);

    dwgelu_v_kernel<<<dim3((HIDDEN_ * 2048 + 255) / 256), blk, 0, stream>>>(
        convout, ffn_dw_w, gated);

    gemm_kernel<true, true><<<dim3(128, 2), blk, 0, stream>>>(
        gated, wfo, out_i, out_i, CDIM, 576, HIDDEN_);  // final = x1 + conv
  }
}

// Round 10
// 638.417 us; speedup vs baseline: 21.0226x; 1.4674x over previous
//
#include <hip/hip_runtime.h>
#include <hip/hip_bf16.h>
#include <math.h>

#define CDIM    192
#define NHEADS  4
#define HDDIM   48
#define HH      128
#define WW      128
#define NPIX    16384      // 128*128
#define OQKV    768
#define HIDDEN_ 510
#define OFFN    1020
#define LNEPS   1e-5f
#define KSPLIT  32
#define PADK    104        // 96 + 8 shorts padding

typedef __hip_bfloat16 bf16;
typedef __attribute__((ext_vector_type(8))) short short8;
typedef __attribute__((ext_vector_type(4))) float f32x4;

__device__ __forceinline__ float b2f(bf16 v) { return __bfloat162float(v); }
__device__ __forceinline__ bf16  f2b(float v) { return __float2bfloat16(v); }
__device__ __forceinline__ unsigned short f2bbits(float v) {
  bf16 h = __float2bfloat16(v);
  return *(unsigned short*)&h;
}
__device__ __forceinline__ float us2f(unsigned short u) {
  union { unsigned int i; float f; } cv; cv.i = ((unsigned int)u) << 16; return cv.f;
}

// ---------------- all weights f32 -> bf16 in one kernel ----------------
__global__ __launch_bounds__(256) void cvt_all_kernel(
    const float* __restrict__ qkv_w, const float* __restrict__ proj_w,
    const float* __restrict__ ffn_in_w, const float* __restrict__ ffn_out_w,
    bf16* __restrict__ wq, bf16* __restrict__ wp,
    bf16* __restrict__ wfi, bf16* __restrict__ wfo) {
  int i = blockIdx.x * 256 + threadIdx.x;
  const int N1 = OQKV * CDIM, N2 = CDIM * CDIM, N3 = OFFN * CDIM, N4 = CDIM * 576;
  if (i < N1) { wq[i] = f2b(qkv_w[i]); return; }
  i -= N1;
  if (i < N2) { wp[i] = f2b(proj_w[i]); return; }
  i -= N2;
  if (i < N3) { wfi[i] = f2b(ffn_in_w[i]); return; }
  i -= N3;
  if (i < N4) {
    int r = i / 576, c = i - r * 576;
    wfo[i] = (c < HIDDEN_) ? f2b(ffn_out_w[r * HIDDEN_ + c]) : f2b(0.f);
  }
}

// ---------------- LayerNorm over channels, per pixel. x:[I][C][N] f32 -> y:[I][N][C] bf16 ----------------
// grid (NPIX/64, IB)
__global__ __launch_bounds__(256) void ln_t_kernel(
    const float* __restrict__ xb, const float* __restrict__ w,
    const float* __restrict__ b, bf16* __restrict__ yb) {
  __shared__ float red[8][64];
  __shared__ float mu_s[64], rs_s[64];
  __shared__ unsigned short tile[64 * 194];
  const int t = threadIdx.x;
  const int n0 = blockIdx.x * 64;
  const int img = blockIdx.y;
  const float* x = xb + (size_t)img * CDIM * NPIX;
  bf16* y = yb + (size_t)img * CDIM * NPIX;   // [N][C] layout, same elem count
  const int p = t & 63, q = t >> 6;

  float s = 0.f, ss = 0.f;
  for (int c = q * 48; c < q * 48 + 48; ++c) {
    float v = x[(size_t)c * NPIX + n0 + p];
    s += v; ss += v * v;
  }
  red[q][p] = s; red[4 + q][p] = ss;
  __syncthreads();
  if (t < 64) {
    float S  = red[0][t] + red[1][t] + red[2][t] + red[3][t];
    float SS = red[4][t] + red[5][t] + red[6][t] + red[7][t];
    float mu = S * (1.f / CDIM);
    float var = SS * (1.f / CDIM) - mu * mu;
    mu_s[t] = mu; rs_s[t] = rsqrtf(var + LNEPS);
  }
  __syncthreads();
  for (int i = 0; i < 48; ++i) {
    int flat = i * 256 + t;
    int c = flat >> 6, p2 = flat & 63;
    float v = (x[(size_t)c * NPIX + n0 + p2] - mu_s[p2]) * rs_s[p2] * w[c] + b[c];
    tile[p2 * 194 + c] = f2bbits(v);
  }
  __syncthreads();
  unsigned short* yo = (unsigned short*)y + (size_t)n0 * CDIM;
  for (int i = 0; i < 48; ++i) {
    int flat = i * 256 + t;
    int pp = flat / 192, cc = flat - pp * 192;
    yo[flat] = tile[pp * 194 + cc];
  }
}

// ---------------- MFMA GEMM (batched): out[i][m][n] = sum_k Wb[m][k]*act[i][k][n] ----------------
// grid (128, M/128, IB). bstride/ostride = per-image element strides.
template <bool BT, bool F32OUT>
__global__ __launch_bounds__(256) void gemm_kernel(
    const bf16* __restrict__ Bact0, const bf16* __restrict__ Wb,
    const float* __restrict__ res0, void* __restrict__ outp,
    int M, int KA, int KB, size_t bstride, size_t ostride) {
  __shared__ __align__(16) unsigned short sA[128 * PADK];
  __shared__ __align__(16) unsigned short sB[128 * PADK];
  const int t = threadIdx.x;
  const int lane = t & 63;
  const int wave = t >> 6;
  const int wm = wave >> 1, wn = wave & 1;
  const int l15 = lane & 15, lk = lane >> 4;
  const int n0 = blockIdx.x * 128;
  const int m0 = blockIdx.y * 128;
  const int img = blockIdx.z;
  const bf16* Bact = Bact0 + (size_t)img * bstride;

  f32x4 acc[4][4];
#pragma unroll
  for (int i = 0; i < 4; ++i)
#pragma unroll
    for (int j = 0; j < 4; ++j) acc[i][j] = (f32x4){0.f, 0.f, 0.f, 0.f};

  const int Ksteps = KA / 96;
  for (int ks = 0; ks < Ksteps; ++ks) {
    const int k0 = ks * 96;
    __syncthreads();
    {
      const int m = t >> 1, half = t & 1;
      const int gm = m0 + m;
      short8 v[6];
      if (gm < M) {
        const short8* src = (const short8*)(Wb + (size_t)gm * KA + k0 + half * 48);
#pragma unroll
        for (int j = 0; j < 6; ++j) v[j] = src[j];
      } else {
#pragma unroll
        for (int j = 0; j < 6; ++j) v[j] = (short8){0,0,0,0,0,0,0,0};
      }
#pragma unroll
      for (int j = 0; j < 6; ++j)
        *(short8*)&sA[m * PADK + half * 48 + j * 8] = v[j];
    }
    if (!BT) {
      const int n = t >> 1, half = t & 1;
      const short8* src = (const short8*)(Bact + (size_t)(n0 + n) * KB + k0 + half * 48);
      short8 v[6];
#pragma unroll
      for (int j = 0; j < 6; ++j) v[j] = src[j];
#pragma unroll
      for (int j = 0; j < 6; ++j)
        *(short8*)&sB[n * PADK + half * 48 + j * 8] = v[j];
    } else {
#pragma unroll
      for (int kk = 0; kk < 3; ++kk) {
        const int k = kk * 32 + (t >> 3), part = t & 7;
        const int gk = k0 + k;
        short8 v0 = {}, v1 = {};
        if (gk < KB) {
          const short8* src = (const short8*)(Bact + (size_t)gk * NPIX + n0 + part * 16);
          v0 = src[0]; v1 = src[1];
        }
#pragma unroll
        for (int j = 0; j < 8; ++j) {
          sB[(part * 16 + j) * PADK + k]     = (unsigned short)v0[j];
          sB[(part * 16 + 8 + j) * PADK + k] = (unsigned short)v1[j];
        }
      }
    }
    __syncthreads();
#pragma unroll
    for (int sk = 0; sk < 3; ++sk) {
      short8 af[4], bf_[4];
#pragma unroll
      for (int mf = 0; mf < 4; ++mf)
        af[mf] = *(const short8*)&sA[(wm * 64 + mf * 16 + l15) * PADK + sk * 32 + lk * 8];
#pragma unroll
      for (int nf = 0; nf < 4; ++nf)
        bf_[nf] = *(const short8*)&sB[(wn * 64 + nf * 16 + l15) * PADK + sk * 32 + lk * 8];
#pragma unroll
      for (int mf = 0; mf < 4; ++mf)
#pragma unroll
        for (int nf = 0; nf < 4; ++nf)
          acc[mf][nf] = __builtin_amdgcn_mfma_f32_16x16x32_bf16(
              af[mf], bf_[nf], acc[mf][nf], 0, 0, 0);
    }
  }

#pragma unroll
  for (int mf = 0; mf < 4; ++mf) {
#pragma unroll
    for (int nf = 0; nf < 4; ++nf) {
#pragma unroll
      for (int r = 0; r < 4; ++r) {
        int m = m0 + wm * 64 + mf * 16 + lk * 4 + r;
        int n = n0 + wn * 64 + nf * 16 + l15;
        if (m < M) {
          size_t off = (size_t)img * ostride + (size_t)m * NPIX + n;
          if (F32OUT) ((float*)outp)[off] = acc[mf][nf][r] + res0[off];
          else        ((bf16*)outp)[off]  = f2b(acc[mf][nf][r]);
        }
      }
    }
  }
}

// ---------------- vectorized depthwise 3x3 (batched): 8 px / thread ----------------
// grid: IB*OQKV*2048/256 = IB*6144. in: R2 [img][1020][N] rows 0..768; out: R3 [img][768][N]
__global__ __launch_bounds__(256) void dwconv_v_kernel(
    const bf16* __restrict__ in, const float* __restrict__ w,
    bf16* __restrict__ out) {
  const int idx = blockIdx.x * 256 + threadIdx.x;
  const int chg = idx >> 11;
  const int img = chg / OQKV;
  const int ch  = chg - img * OQKV;
  const int rem = idx & 2047;
  const int y = rem >> 4;
  const int x8 = (rem & 15) * 8;
  const unsigned short* ip = (const unsigned short*)in + (size_t)img * OFFN * NPIX + (size_t)ch * NPIX;
  const float* wp = w + ch * 9;

  float acc[8];
#pragma unroll
  for (int i = 0; i < 8; ++i) acc[i] = 0.f;

#pragma unroll
  for (int ky = 0; ky < 3; ++ky) {
    int yy = y + ky - 1;
    if (yy < 0 || yy >= HH) continue;
    const unsigned short* rp = ip + yy * WW + x8;
    float vals[10];
    short8 mv = *(const short8*)rp;
    vals[0] = (x8 > 0) ? us2f(rp[-1]) : 0.f;
#pragma unroll
    for (int j = 0; j < 8; ++j) vals[1 + j] = us2f((unsigned short)mv[j]);
    vals[9] = (x8 + 8 < WW) ? us2f(rp[8]) : 0.f;
    float w0 = wp[ky * 3], w1 = wp[ky * 3 + 1], w2 = wp[ky * 3 + 2];
#pragma unroll
    for (int xx = 0; xx < 8; ++xx)
      acc[xx] += w0 * vals[xx] + w1 * vals[xx + 1] + w2 * vals[xx + 2];
  }

  short8 o;
#pragma unroll
  for (int xx = 0; xx < 8; ++xx) o[xx] = (short)f2bbits(acc[xx]);
  *(short8*)((unsigned short*)out + (size_t)img * OQKV * NPIX + (size_t)ch * NPIX + y * WW + x8) = o;
}

// ---------------- vectorized fused FFN dwconv3x3 + gelu(x1)*x2 (batched) ----------------
// grid: IB*510*2048/256 = IB*4080. in: R2 [img][1020][N]; out: R3 [img][768-slot][N] rows 0..510
__global__ __launch_bounds__(256) void dwgelu_v_kernel(
    const bf16* __restrict__ in, const float* __restrict__ w,
    bf16* __restrict__ out) {
  const int idx = blockIdx.x * 256 + threadIdx.x;
  const int chg = idx >> 11;
  const int img = chg / HIDDEN_;
  const int ch  = chg - img * HIDDEN_;
  const int rem = idx & 2047;
  const int y = rem >> 4;
  const int x8 = (rem & 15) * 8;
  const unsigned short* ip1 = (const unsigned short*)in + (size_t)img * OFFN * NPIX + (size_t)ch * NPIX;
  const unsigned short* ip2 = ip1 + (size_t)HIDDEN_ * NPIX;
  const float* wp1 = w + ch * 9;
  const float* wp2 = w + (ch + HIDDEN_) * 9;

  float a1[8], a2[8];
#pragma unroll
  for (int i = 0; i < 8; ++i) { a1[i] = 0.f; a2[i] = 0.f; }

#pragma unroll
  for (int ky = 0; ky < 3; ++ky) {
    int yy = y + ky - 1;
    if (yy < 0 || yy >= HH) continue;
    {
      const unsigned short* rp = ip1 + yy * WW + x8;
      float vals[10];
      short8 mv = *(const short8*)rp;
      vals[0] = (x8 > 0) ? us2f(rp[-1]) : 0.f;
#pragma unroll
      for (int j = 0; j < 8; ++j) vals[1 + j] = us2f((unsigned short)mv[j]);
      vals[9] = (x8 + 8 < WW) ? us2f(rp[8]) : 0.f;
      float w0 = wp1[ky * 3], w1 = wp1[ky * 3 + 1], w2 = wp1[ky * 3 + 2];
#pragma unroll
      for (int xx = 0; xx < 8; ++xx)
        a1[xx] += w0 * vals[xx] + w1 * vals[xx + 1] + w2 * vals[xx + 2];
    }
    {
      const unsigned short* rp = ip2 + yy * WW + x8;
      float vals[10];
      short8 mv = *(const short8*)rp;
      vals[0] = (x8 > 0) ? us2f(rp[-1]) : 0.f;
#pragma unroll
      for (int j = 0; j < 8; ++j) vals[1 + j] = us2f((unsigned short)mv[j]);
      vals[9] = (x8 + 8 < WW) ? us2f(rp[8]) : 0.f;
      float w0 = wp2[ky * 3], w1 = wp2[ky * 3 + 1], w2 = wp2[ky * 3 + 2];
#pragma unroll
      for (int xx = 0; xx < 8; ++xx)
        a2[xx] += w0 * vals[xx] + w1 * vals[xx + 1] + w2 * vals[xx + 2];
    }
  }

  short8 o;
#pragma unroll
  for (int xx = 0; xx < 8; ++xx) {
    float ge = 0.5f * a1[xx] * (1.f + erff(a1[xx] * 0.70710678118f));
    o[xx] = (short)f2bbits(ge * a2[xx]);
  }
  *(short8*)((unsigned short*)out + (size_t)img * OQKV * NPIX + (size_t)ch * NPIX + y * WW + x8) = o;
}

// ---------------- per-channel 1/max(||row||,1e-12) for q and k (batched, short8) ----------------
// grid (384, IB)
__global__ __launch_bounds__(256) void rnorm_kernel(
    const bf16* __restrict__ qkvg, float* __restrict__ rn) {
  int ci = blockIdx.x;
  int img = blockIdx.y;
  int ch = (ci < 192) ? ci : (ci + 192);
  const unsigned short* p = (const unsigned short*)qkvg + (size_t)img * OQKV * NPIX + (size_t)ch * NPIX;
  float s = 0.f;
  for (int i = threadIdx.x * 8; i < NPIX; i += 256 * 8) {
    short8 v = *(const short8*)(p + i);
#pragma unroll
    for (int j = 0; j < 8; ++j) { float f = us2f((unsigned short)v[j]); s += f * f; }
  }
  for (int off = 32; off; off >>= 1) s += __shfl_down(s, off);
  __shared__ float red[4];
  int wave = threadIdx.x >> 6, lane = threadIdx.x & 63;
  if (lane == 0) red[wave] = s;
  __syncthreads();
  if (threadIdx.x == 0) {
    float tsum = red[0] + red[1] + red[2] + red[3];
    rn[img * 384 + ci] = 1.f / fmaxf(sqrtf(tsum), 1e-12f);
  }
}

// ---------------- attention logits via split-K MFMA (batched) ----------------
// grid (KSPLIT, NHEADS, IB), block 64
__global__ __launch_bounds__(64) void attn_logits_kernel(
    const bf16* __restrict__ qkvg, float* __restrict__ part) {
  const int ks = blockIdx.x, h = blockIdx.y, img = blockIdx.z;
  const int lane = threadIdx.x;
  const int l15 = lane & 15, lk = lane >> 4;
  const bf16* qbase = qkvg + (size_t)img * OQKV * NPIX + (size_t)(h * HDDIM) * NPIX;
  const bf16* kbase = qkvg + (size_t)img * OQKV * NPIX + (size_t)(384 + h * HDDIM) * NPIX;

  f32x4 acc[3][3];
#pragma unroll
  for (int i = 0; i < 3; ++i)
#pragma unroll
    for (int j = 0; j < 3; ++j) acc[i][j] = (f32x4){0.f, 0.f, 0.f, 0.f};

  const int n_start = ks * (NPIX / KSPLIT);   // 512-px chunk
  for (int n0 = n_start; n0 < n_start + NPIX / KSPLIT; n0 += 32) {
    short8 af[3], bfr[3];
#pragma unroll
    for (int i = 0; i < 3; ++i)
      af[i] = *(const short8*)(qbase + (size_t)(i * 16 + l15) * NPIX + n0 + lk * 8);
#pragma unroll
    for (int j = 0; j < 3; ++j)
      bfr[j] = *(const short8*)(kbase + (size_t)(j * 16 + l15) * NPIX + n0 + lk * 8);
#pragma unroll
    for (int i = 0; i < 3; ++i)
#pragma unroll
      for (int j = 0; j < 3; ++j)
        acc[i][j] = __builtin_amdgcn_mfma_f32_16x16x32_bf16(af[i], bfr[j], acc[i][j], 0, 0, 0);
  }

  float* pp = part + ((size_t)img * KSPLIT * NHEADS + (size_t)(ks * NHEADS + h)) * (HDDIM * HDDIM);
#pragma unroll
  for (int i = 0; i < 3; ++i)
#pragma unroll
    for (int j = 0; j < 3; ++j)
#pragma unroll
      for (int r = 0; r < 4; ++r) {
        int row = i * 16 + lk * 4 + r;
        int col = j * 16 + l15;
        pp[row * HDDIM + col] = acc[i][j][r];
      }
}

// ---------------- reduce partials + scale + softmax (batched) ----------------
// grid (192, IB), block 64
__global__ __launch_bounds__(64) void attn_softmax_kernel(
    const float* __restrict__ part, const float* __restrict__ rn,
    const float* __restrict__ temp, float* __restrict__ attn) {
  int g = blockIdx.x;
  int img = blockIdx.y;
  int h = g / HDDIM, c = g % HDDIM;
  int d = threadIdx.x;
  float v = 0.f;
  if (d < HDDIM) {
    const float* pb = part + (size_t)img * KSPLIT * NHEADS * HDDIM * HDDIM;
    for (int ks = 0; ks < KSPLIT; ++ks)
      v += pb[((size_t)(ks * NHEADS + h)) * (HDDIM * HDDIM) + c * HDDIM + d];
    v *= rn[img * 384 + g] * rn[img * 384 + 192 + h * HDDIM + d] * temp[h];
  }
  float lv = (d < HDDIM) ? v : -1e30f;
  float m = lv;
  for (int off = 32; off; off >>= 1) m = fmaxf(m, __shfl_xor(m, off));
  float e = (d < HDDIM) ? expf(lv - m) : 0.f;
  float s = e;
  for (int off = 32; off; off >>= 1) s += __shfl_xor(s, off);
  if (d < HDDIM) attn[((size_t)img * CDIM + g) * HDDIM + d] = e / s;
}

// ---------------- out = (attn @ v) * sigmoid(gate) -> [img][C][N] bf16 (8 px/thread) ----------------
// grid (8, 48, IB*4)
__global__ __launch_bounds__(256) void attnout_v_kernel(
    const bf16* __restrict__ qkvg, const float* __restrict__ attn,
    bf16* __restrict__ out) {
  const int n8 = (blockIdx.x * 256 + threadIdx.x) * 8;   // pixel base
  const int c = blockIdx.y;
  const int z = blockIdx.z;
  const int img = z >> 2, h = z & 3;
  const int g = h * HDDIM + c;
  __shared__ float a[HDDIM];
  if (threadIdx.x < HDDIM)
    a[threadIdx.x] = attn[((size_t)img * CDIM + g) * HDDIM + threadIdx.x];
  __syncthreads();
  const unsigned short* vbase = (const unsigned short*)qkvg +
      (size_t)img * OQKV * NPIX + (size_t)(576 + h * HDDIM) * NPIX + n8;
  float acc[8];
#pragma unroll
  for (int j = 0; j < 8; ++j) acc[j] = 0.f;
  for (int d = 0; d < HDDIM; ++d) {
    short8 vv = *(const short8*)(vbase + (size_t)d * NPIX);
    float ad = a[d];
#pragma unroll
    for (int j = 0; j < 8; ++j) acc[j] += ad * us2f((unsigned short)vv[j]);
  }
  short8 gv = *(const short8*)((const unsigned short*)qkvg +
      (size_t)img * OQKV * NPIX + (size_t)(192 + g) * NPIX + n8);
  short8 o;
#pragma unroll
  for (int j = 0; j < 8; ++j) {
    float gate = us2f((unsigned short)gv[j]);
    float sg = 1.f / (1.f + expf(-gate));
    o[j] = (short)f2bbits(acc[j] * sg);
  }
  *(short8*)((unsigned short*)out + (size_t)img * CDIM * NPIX + (size_t)g * NPIX + n8) = o;
}

extern "C" void kernel_launch(void* const* d_in, const int* in_sizes, int n_in,
                              void* d_out, int out_size, void* d_ws, size_t ws_size,
                              hipStream_t stream) {
  const float* x        = (const float*)d_in[0];
  const float* ln1_w    = (const float*)d_in[1];
  const float* ln1_b    = (const float*)d_in[2];
  const float* qkv_w    = (const float*)d_in[3];
  const float* qkv_dw_w = (const float*)d_in[4];
  const float* temp     = (const float*)d_in[5];
  const float* proj_w   = (const float*)d_in[6];
  const float* ln2_w    = (const float*)d_in[7];
  const float* ln2_b    = (const float*)d_in[8];
  const float* ffn_in_w = (const float*)d_in[9];
  const float* ffn_dw_w = (const float*)d_in[10];
  const float* ffn_out_w= (const float*)d_in[11];
  float* out = (float*)d_out;

  const size_t R1E = (size_t)NPIX * CDIM;    // per-img elems (bf16)
  const size_t R2E = (size_t)NPIX * OFFN;
  const size_t R3E = (size_t)NPIX * OQKV;
  const size_t WQE = (size_t)OQKV * CDIM, WPE = (size_t)CDIM * CDIM;
  const size_t WFIE = (size_t)OFFN * CDIM, WFOE = (size_t)CDIM * 576;
  const size_t PARTE = (size_t)KSPLIT * NHEADS * HDDIM * HDDIM;  // f32 per img
  const size_t ATTME = (size_t)CDIM * HDDIM;                     // f32 per img

  auto need = [&](int I) -> size_t {
    return (size_t)I * (R1E + R2E + R3E) * 2 +
           (WQE + WPE + WFIE + WFOE) * 2 +
           (size_t)I * (PARTE + ATTME + 384) * 4;
  };
  const int IB = (need(4) <= ws_size) ? 4 : ((need(2) <= ws_size) ? 2 : 1);

  char* p = (char*)d_ws;
  bf16*  R1  = (bf16*)p;  p += (size_t)IB * R1E * 2;   // lnout / attout
  bf16*  R2  = (bf16*)p;  p += (size_t)IB * R2E * 2;   // convout / ffnbuf
  bf16*  R3  = (bf16*)p;  p += (size_t)IB * R3E * 2;   // qkvg / gated
  bf16*  wq  = (bf16*)p;  p += WQE * 2;
  bf16*  wp_ = (bf16*)p;  p += WPE * 2;
  bf16*  wfi = (bf16*)p;  p += WFIE * 2;
  bf16*  wfo = (bf16*)p;  p += WFOE * 2;
  float* partial = (float*)p; p += (size_t)IB * PARTE * 4;
  float* attnm   = (float*)p; p += (size_t)IB * ATTME * 4;
  float* rn      = (float*)p; p += (size_t)IB * 384 * 4;

  dim3 blk(256);

  cvt_all_kernel<<<dim3((unsigned)((WQE + WPE + WFIE + WFOE) / 256)), blk, 0, stream>>>(
      qkv_w, proj_w, ffn_in_w, ffn_out_w, wq, wp_, wfi, wfo);

  for (int b0 = 0; b0 < 4; b0 += IB) {
    const float* x_b = x + (size_t)b0 * CDIM * NPIX;
    float* out_b = out + (size_t)b0 * CDIM * NPIX;

    // ---- attention branch ----
    ln_t_kernel<<<dim3(NPIX / 64, IB), blk, 0, stream>>>(x_b, ln1_w, ln1_b, R1);

    gemm_kernel<false, false><<<dim3(128, OQKV / 128, IB), blk, 0, stream>>>(
        R1, wq, nullptr, R2, OQKV, CDIM, CDIM, R1E, R2E);

    dwconv_v_kernel<<<dim3(IB * 6144), blk, 0, stream>>>(R2, qkv_dw_w, R3);

    rnorm_kernel<<<dim3(384, IB), blk, 0, stream>>>(R3, rn);

    attn_logits_kernel<<<dim3(KSPLIT, NHEADS, IB), dim3(64), 0, stream>>>(R3, partial);

    attn_softmax_kernel<<<dim3(CDIM, IB), dim3(64), 0, stream>>>(partial, rn, temp, attnm);

    attnout_v_kernel<<<dim3(8, HDDIM, IB * NHEADS), blk, 0, stream>>>(R3, attnm, R1);

    gemm_kernel<true, true><<<dim3(128, 2, IB), blk, 0, stream>>>(
        R1, wp_, x_b, out_b, CDIM, CDIM, CDIM, R1E, R1E);   // x1 -> d_out (f32 stride=CDIM*NPIX=R1E)

    // ---- ffn branch ----
    ln_t_kernel<<<dim3(NPIX / 64, IB), blk, 0, stream>>>(out_b, ln2_w, ln2_b, R1);

    gemm_kernel<false, false><<<dim3(128, 8, IB), blk, 0, stream>>>(
        R1, wfi, nullptr, R2, OFFN, CDIM, CDIM, R1E, R2E);

    dwgelu_v_kernel<<<dim3(IB * 4080), blk, 0, stream>>>(R2, ffn_dw_w, R3);

    gemm_kernel<true, true><<<dim3(128, 2, IB), blk, 0, stream>>>(
        R3, wfo, out_b, out_b, CDIM, 576, HIDDEN_, R3E, R1E); // final = x1 + conv
  }
}